// Round 2
// baseline (4789.403 us; speedup 1.0000x reference)
//
#include <hip/hip_runtime.h>
#include <math.h>

#define NPTS  32768
#define NB    2
#define NQ    (NB*NPTS)
#define KK    16
#define EPS   1e-6f
#define G     64
#define G3    (G*G*G)
#define SLOP  0.05f

// stats / coef element offsets
#define S_L1 0
#define S_L2 32
#define S_P1 64
#define S_P2 96
#define S_SC 160
#define C_L1 0
#define C_L2 32
#define C_P1 64
#define C_P2 96
#define C_SC 160

// workspace element offsets (4-byte units)
#define WS_X1    (NQ*16)
#define WS_T2    (NQ*32)
#define WS_T4    (NQ*48)
#define WS_STAT  (NQ*80)
#define WS_COEF  (NQ*80 + 512)
#define WS_GCNT  (NQ*80 + 1024)
#define WS_GSTART (WS_GCNT + 2*G3)
#define WS_CELLID (WS_GSTART + 2*G3)
#define WS_GIDS   (WS_CELLID + NQ)
#define WS_BBOX   (WS_GIDS + NQ)
#define WS_GTOT   (WS_BBOX + 12)

__device__ __forceinline__ float wred64(float v) {
#pragma unroll
  for (int m = 32; m > 0; m >>= 1) v += __shfl_xor(v, m, 64);
  return v;
}

// order-preserving float <-> uint encoding for atomic min/max
__device__ __forceinline__ unsigned int encf(float f) {
  unsigned int u = __float_as_uint(f);
  return (u & 0x80000000u) ? ~u : (u | 0x80000000u);
}
__device__ __forceinline__ float decf(unsigned int u) {
  return (u & 0x80000000u) ? __uint_as_float(u & 0x7fffffffu) : __uint_as_float(~u);
}

// ---------------- zero stats + grid counters + bbox init ----------------
__global__ void k_zero_all(float* __restrict__ stats, int* __restrict__ gcnt,
                           unsigned int* __restrict__ bbox, int* __restrict__ gtot) {
  int i = blockIdx.x*256 + threadIdx.x;      // grid sized to cover 2*G3
  if (i < 2*G3) gcnt[i] = 0;
  if (i < 320)  stats[i] = 0.f;
  if (i < 12)   bbox[i] = ((i % 6) < 3) ? 0xFFFFFFFFu : 0u;  // mins / maxs
  if (i < 2)    gtot[i] = 0;
}

// ---------------- per-batch exact bounding box ----------------
__global__ void k_bbox(const float* __restrict__ coords, unsigned int* __restrict__ bbox) {
  __shared__ unsigned int rmn[3][4], rmx[3][4];
  int tid = threadIdx.x;
  int t = blockIdx.x*256 + tid;
  int b = t >> 15, n = t & (NPTS-1);
  const float* cb = coords + (size_t)b*(NPTS*3);
  unsigned int e[3] = { encf(cb[n*3+0]), encf(cb[n*3+1]), encf(cb[n*3+2]) };
  unsigned int mn[3] = { e[0], e[1], e[2] }, mx[3] = { e[0], e[1], e[2] };
#pragma unroll
  for (int s = 32; s > 0; s >>= 1) {
#pragma unroll
    for (int a = 0; a < 3; ++a) {
      unsigned int o1 = (unsigned int)__shfl_xor((int)mn[a], s, 64);
      unsigned int o2 = (unsigned int)__shfl_xor((int)mx[a], s, 64);
      mn[a] = mn[a] < o1 ? mn[a] : o1;
      mx[a] = mx[a] > o2 ? mx[a] : o2;
    }
  }
  int wave = tid >> 6, lane = tid & 63;
  if (lane == 0) {
#pragma unroll
    for (int a = 0; a < 3; ++a) { rmn[a][wave] = mn[a]; rmx[a][wave] = mx[a]; }
  }
  __syncthreads();
  if (tid < 3) {
    unsigned int a0 = min(min(rmn[tid][0], rmn[tid][1]), min(rmn[tid][2], rmn[tid][3]));
    unsigned int A0 = max(max(rmx[tid][0], rmx[tid][1]), max(rmx[tid][2], rmx[tid][3]));
    atomicMin(&bbox[b*6 + tid], a0);
    atomicMax(&bbox[b*6 + 3 + tid], A0);
  }
}

// ---------------- bin points into cells ----------------
__global__ void k_bin(const float* __restrict__ coords, const unsigned int* __restrict__ bbox,
                      int* __restrict__ cellid, int* __restrict__ gcnt) {
  int t = blockIdx.x*256 + threadIdx.x;
  int b = t >> 15, n = t & (NPTS-1);
  const float* cb = coords + (size_t)b*(NPTS*3);
  int cc[3];
#pragma unroll
  for (int a = 0; a < 3; ++a) {
    float l = decf(bbox[b*6+a]), h = decf(bbox[b*6+3+a]);
    float exx = (h - l)*(1.f + 4e-7f) + 1e-30f;
    float invv = (float)G / exx;
    int c = (int)((cb[n*3+a] - l)*invv);
    cc[a] = min(G-1, max(0, c));
  }
  int cid = b*G3 + (cc[2]*G + cc[1])*G + cc[0];
  cellid[t] = cid;
  atomicAdd(&gcnt[cid], 1);
}

// ---------------- allocate per-cell ranges (block scan + 1 atomic/block) ----------------
__global__ void k_alloc(const int* __restrict__ gcnt, int* __restrict__ gstart,
                        int* __restrict__ gtot) {
  __shared__ int ssum[256]; __shared__ int sbase;
  int tid = threadIdx.x;
  int c0 = blockIdx.x*2048 + tid*8;           // 2048 cells/block, 2048 | G3 -> no batch straddle
  int v[8]; int s = 0;
#pragma unroll
  for (int i = 0; i < 8; ++i) { v[i] = gcnt[c0+i]; s += v[i]; }
  ssum[tid] = s;
  __syncthreads();
  for (int off = 1; off < 256; off <<= 1) {
    int x = ssum[tid];
    int y = (tid >= off) ? ssum[tid-off] : 0;
    __syncthreads();
    ssum[tid] = x + y;
    __syncthreads();
  }
  if (tid == 255) sbase = atomicAdd(&gtot[c0 / G3], ssum[255]);
  __syncthreads();
  int base = sbase + ssum[tid] - s;           // exclusive prefix for this thread
#pragma unroll
  for (int i = 0; i < 8; ++i) { gstart[c0+i] = base; base += v[i]; }
}

// ---------------- scatter point ids into cell lists ----------------
__global__ void k_scatter(const int* __restrict__ cellid, int* __restrict__ gstart,
                          int* __restrict__ gids) {
  int t = blockIdx.x*256 + threadIdx.x;
  int b = t >> 15, n = t & (NPTS-1);
  int cid = cellid[t];
  int pos = atomicAdd(&gstart[cid], 1);       // after this kernel gstart[c] = base + count
  gids[b*NPTS + pos] = n;
}

// ---------------- exact KNN via expanding grid shells ----------------
__launch_bounds__(256)
__global__ void k_knn_grid(const float* __restrict__ coords,
                           const int* __restrict__ gcnt, const int* __restrict__ gstart,
                           const int* __restrict__ gids, const unsigned int* __restrict__ bbox,
                           int* __restrict__ oidx) {
  int t = blockIdx.x*256 + threadIdx.x;       // cell-sorted query order (L2 locality)
  int b = t >> 15;
  int qn = gids[t];                           // batch-local query point id
  const float* __restrict__ cb = coords + (size_t)b*(NPTS*3);
  float lo[3], hx[3], inv[3];
#pragma unroll
  for (int a = 0; a < 3; ++a) {
    float l = decf(bbox[b*6+a]), h = decf(bbox[b*6+3+a]);
    float exx = (h - l)*(1.f + 4e-7f) + 1e-30f;
    lo[a] = l; hx[a] = exx*(1.f/(float)G); inv[a] = (float)G/exx;
  }
  const float qx = cb[qn*3+0], qy = cb[qn*3+1], qz = cb[qn*3+2];
  const float qsq = qx*qx + qy*qy + qz*qz;
  int cx = min(G-1, max(0, (int)((qx - lo[0])*inv[0])));
  int cy = min(G-1, max(0, (int)((qy - lo[1])*inv[1])));
  int cz = min(G-1, max(0, (int)((qz - lo[2])*inv[2])));

  float dl[KK]; int il[KK];
#pragma unroll
  for (int i = 0; i < KK; ++i) { dl[i] = 1e30f; il[i] = 0; }

  auto proc = [&](int x, int y, int z) {
    int c = b*G3 + (z*G + y)*G + x;
    int e = gstart[c], s0 = e - gcnt[c];
    for (int i = s0; i < e; ++i) {
      int j = gids[b*NPTS + i];
      float px = cb[j*3+0], py = cb[j*3+1], pz = cb[j*3+2];
      float psq = px*px + py*py + pz*pz;
      float d = qsq + psq - 2.f*(qx*px + qy*py + qz*pz);   // == round-1 / reference formula
      if (d < dl[KK-1]) {                                   // strict <
        float cd = d; int ci = j;
#pragma unroll
        for (int i2 = 0; i2 < KK; ++i2) {
          bool sw = cd < dl[i2];
          float td = dl[i2]; int ti = il[i2];
          dl[i2] = sw ? cd : td; il[i2] = sw ? ci : ti;
          cd = sw ? td : cd;    ci = sw ? ti : ci;
        }
      }
    }
  };

  for (int r = 0; r <= G; ++r) {
    if (r >= 1 && dl[KK-1] < 1e29f) {
      // min distance from q to outside the already-searched region (cells +-(r-1))
      int rm = r - 1;
      float m = 1e30f;
      if (cx-rm > 0)   m = fminf(m, qx - (lo[0] + (float)(cx-rm)*hx[0]));
      if (cx+rm < G-1) m = fminf(m, (lo[0] + (float)(cx+rm+1)*hx[0]) - qx);
      if (cy-rm > 0)   m = fminf(m, qy - (lo[1] + (float)(cy-rm)*hx[1]));
      if (cy+rm < G-1) m = fminf(m, (lo[1] + (float)(cy+rm+1)*hx[1]) - qy);
      if (cz-rm > 0)   m = fminf(m, qz - (lo[2] + (float)(cz-rm)*hx[2]));
      if (cz+rm < G-1) m = fminf(m, (lo[2] + (float)(cz+rm+1)*hx[2]) - qz);
      if (m > 0.f && m*m > dl[KK-1] + SLOP) break;
    }
    int zlo = max(cz-r, 0), zhi = min(cz+r, G-1);
    for (int z = zlo; z <= zhi; ++z) {
      bool zf = (z == cz-r) || (z == cz+r);
      int ylo = max(cy-r, 0), yhi = min(cy+r, G-1);
      for (int y = ylo; y <= yhi; ++y) {
        bool yf = (y == cy-r) || (y == cy+r);
        if (zf || yf) {
          int xlo = max(cx-r, 0), xhi = min(cx+r, G-1);
          for (int x = xlo; x <= xhi; ++x) proc(x, y, z);
        } else {
          if (cx-r >= 0)   proc(cx-r, y, z);
          if (cx+r <= G-1) proc(cx+r, y, z);
        }
      }
    }
  }
#pragma unroll
  for (int i = 0; i < KK; ++i) oidx[((size_t)(b*NPTS + qn))*KK + i] = il[i];
}

// ---------------- mlp1 (leaky 0.2) + shortcut BN stats ----------------
__global__ void k_mlp1(const float* __restrict__ features,
                       const float* __restrict__ W1, const float* __restrict__ b1,
                       const float* __restrict__ Wsc, const float* __restrict__ bsc,
                       float* __restrict__ x1, float* __restrict__ stats) {
  __shared__ float sW1[128], sb1[16], sWsc[512], sbsc[64];
  int tid = threadIdx.x;
  if (tid < 128) sW1[tid] = W1[tid];
  if (tid < 16)  sb1[tid] = b1[tid];
  if (tid < 64)  sbsc[tid] = bsc[tid];
  for (int i = tid; i < 512; i += 256) sWsc[i] = Wsc[i];
  __syncthreads();
  int q = blockIdx.x*256 + tid;
  int b = q >> 15, n = q & (NPTS-1);
  float f[8];
#pragma unroll
  for (int c = 0; c < 8; ++c) f[c] = features[((size_t)b*8 + c)*NPTS + n];
#pragma unroll
  for (int co = 0; co < 16; ++co) {
    float a = sb1[co];
#pragma unroll
    for (int c = 0; c < 8; ++c) a += f[c]*sW1[co*8+c];
    x1[(size_t)q*16 + co] = a > 0.f ? a : 0.2f*a;
  }
  int lane = tid & 63;
#pragma unroll
  for (int co = 0; co < 64; ++co) {
    float a = sbsc[co];
#pragma unroll
    for (int c = 0; c < 8; ++c) a += f[c]*sWsc[co*8+c];
    float s = wred64(a), ss = wred64(a*a);
    if (lane == 0) { atomicAdd(&stats[S_SC+co], s); atomicAdd(&stats[S_SC+64+co], ss); }
  }
}

// ---------------- BN stats for BOTH LSE geometric encodings ----------------
__global__ void k_lsestats(const float* __restrict__ coords, const int* __restrict__ idx,
                           const float* __restrict__ Wl1, const float* __restrict__ bl1,
                           const float* __restrict__ Wl2, const float* __restrict__ bl2,
                           float* __restrict__ stats) {
  __shared__ float sW1[160], sb1[16], sW2[160], sb2[16];
  __shared__ float red[4][64];
  int tid = threadIdx.x;
  for (int i = tid; i < 160; i += 256) { sW1[i] = Wl1[i]; sW2[i] = Wl2[i]; }
  if (tid < 16) { sb1[tid] = bl1[tid]; sb2[tid] = bl2[tid]; }
  __syncthreads();
  int t = blockIdx.x*256 + tid;         // (b,n,k) flat
  int q = t >> 4;
  int b = q >> 15, n = q & (NPTS-1);
  const float* cb = coords + (size_t)b*(NPTS*3);
  int j = idx[t];
  float cx = cb[n*3], cy = cb[n*3+1], cz = cb[n*3+2];
  float px = cb[j*3], py = cb[j*3+1], pz = cb[j*3+2];
  float cat[10] = {cx,cy,cz,px,py,pz,cx-px,cy-py,cz-pz,1.f};
  int wave = tid >> 6, lane = tid & 63;
#pragma unroll
  for (int co = 0; co < 16; ++co) {
    float a1 = sb1[co], a2 = sb2[co];
#pragma unroll
    for (int d0 = 0; d0 < 10; ++d0) { a1 += cat[d0]*sW1[co*10+d0]; a2 += cat[d0]*sW2[co*10+d0]; }
    float s1 = wred64(a1), q1 = wred64(a1*a1);
    float s2 = wred64(a2), q2 = wred64(a2*a2);
    if (lane == 0) { red[wave][co]=s1; red[wave][16+co]=q1; red[wave][32+co]=s2; red[wave][48+co]=q2; }
  }
  __syncthreads();
  if (tid < 64) {
    float v = red[0][tid] + red[1][tid] + red[2][tid] + red[3][tid];
    int grp = tid >> 4, c = tid & 15;
    int off = (grp == 0) ? (S_L1 + c) : (grp == 1) ? (S_L1 + 16 + c)
            : (grp == 2) ? (S_L2 + c) : (S_L2 + 16 + c);
    atomicAdd(&stats[off], v);
  }
}

// ---------------- BN finalize ----------------
__global__ void k_bnfin(const float* __restrict__ stats, float* __restrict__ coef,
                        const float* __restrict__ gam, const float* __restrict__ bet,
                        int soff, int coff, int nch, float invc) {
  int c = threadIdx.x;
  if (c < nch) {
    float m = stats[soff + c]*invc;
    float v = stats[soff + nch + c]*invc - m*m;
    float a = gam[c]*rsqrtf(v + EPS);
    coef[coff + c] = a;
    coef[coff + nch + c] = bet[c] - m*a;
  }
}

// ---------------- LSE1 + attentive pooling 1 ----------------
__launch_bounds__(256)
__global__ void k_att1(const float* __restrict__ coords, const int* __restrict__ idx,
                       const float* __restrict__ x1ws,
                       const float* __restrict__ Wl1, const float* __restrict__ bl1,
                       const float* __restrict__ Ws1, const float* __restrict__ Wp1,
                       const float* __restrict__ bp1, const float* __restrict__ coef,
                       float* __restrict__ t2, float* __restrict__ stats) {
  __shared__ float sWl[160], sbl[16];
  __shared__ float sWs[1024];
  __shared__ float sWpT[512], sbp[16];
  __shared__ float lsum[16], lsq[16];
  int tid = threadIdx.x;
  for (int i = tid; i < 160; i += 256) { int c = i/10; sWl[i] = Wl1[i]*coef[C_L1 + c]; }
  if (tid < 16) sbl[tid] = bl1[tid]*coef[C_L1+tid] + coef[C_L1+16+tid];
  for (int i = tid; i < 1024; i += 256) sWs[i] = Ws1[i];
  for (int i = tid; i < 512; i += 256) { int co = i >> 4, cp = i & 15; sWpT[i] = Wp1[cp*32 + co]; }
  if (tid < 16) { sbp[tid] = bp1[tid]; lsum[tid] = 0.f; lsq[tid] = 0.f; }
  __syncthreads();
  int gp = blockIdx.x*16 + (tid >> 4);
  int k  = tid & 15;
  int b = gp >> 15, n = gp & (NPTS-1);
  const float* cb = coords + (size_t)b*(NPTS*3);
  int j = idx[(size_t)gp*KK + k];
  float cx = cb[n*3], cy = cb[n*3+1], cz = cb[n*3+2];
  float px = cb[j*3], py = cb[j*3+1], pz = cb[j*3+2];
  float cat[10] = {cx,cy,cz,px,py,pz,cx-px,cy-py,cz-pz,1.f};
  float x[32];
#pragma unroll
  for (int co = 0; co < 16; ++co) {
    float a = sbl[co];
#pragma unroll
    for (int d0 = 0; d0 < 10; ++d0) a += cat[d0]*sWl[co*10+d0];
    x[co] = a > 0.f ? a : 0.f;
  }
  {
    const float4* xp = (const float4*)(x1ws + (size_t)gp*16);
    float4 u0 = xp[0], u1 = xp[1], u2 = xp[2], u3 = xp[3];
    x[16]=u0.x; x[17]=u0.y; x[18]=u0.z; x[19]=u0.w;
    x[20]=u1.x; x[21]=u1.y; x[22]=u1.z; x[23]=u1.w;
    x[24]=u2.x; x[25]=u2.y; x[26]=u2.z; x[27]=u2.w;
    x[28]=u3.x; x[29]=u3.y; x[30]=u3.z; x[31]=u3.w;
  }
  float tacc = sbp[k];
#pragma unroll
  for (int co = 0; co < 32; ++co) {
    float s = 0.f;
#pragma unroll
    for (int ci = 0; ci < 32; ++ci) s += x[ci]*sWs[co*32+ci];
    float m = s;
#pragma unroll
    for (int msk = 8; msk > 0; msk >>= 1) m = fmaxf(m, __shfl_xor(m, msk, 16));
    float e = __expf(s - m);
    float se = e;
#pragma unroll
    for (int msk = 8; msk > 0; msk >>= 1) se += __shfl_xor(se, msk, 16);
    float w = e/se;
    float fv = w*x[co];
#pragma unroll
    for (int msk = 8; msk > 0; msk >>= 1) fv += __shfl_xor(fv, msk, 16);
    tacc += fv*sWpT[co*16+k];
  }
  t2[(size_t)gp*16 + k] = tacc;
  atomicAdd(&lsum[k], tacc);
  atomicAdd(&lsq[k], tacc*tacc);
  __syncthreads();
  if (tid < 16) { atomicAdd(&stats[S_P1+tid], lsum[tid]); atomicAdd(&stats[S_P1+16+tid], lsq[tid]); }
}

// ---------------- LSE2 + attentive pooling 2 ----------------
__launch_bounds__(256)
__global__ void k_att2(const float* __restrict__ coords, const int* __restrict__ idx,
                       const float* __restrict__ t2ws,
                       const float* __restrict__ Wl2, const float* __restrict__ bl2,
                       const float* __restrict__ Ws2, const float* __restrict__ Wp2,
                       const float* __restrict__ bp2, const float* __restrict__ coef,
                       float* __restrict__ t4, float* __restrict__ stats) {
  __shared__ float sWl[160], sbl[16];
  __shared__ float sWs[1024];
  __shared__ float sWpT[1024], sbp[32];
  __shared__ float sa1[16], sc1[16];
  __shared__ float lsum[32], lsq[32];
  int tid = threadIdx.x;
  for (int i = tid; i < 160; i += 256) { int c = i/10; sWl[i] = Wl2[i]*coef[C_L2 + c]; }
  if (tid < 16) sbl[tid] = bl2[tid]*coef[C_L2+tid] + coef[C_L2+16+tid];
  for (int i = tid; i < 1024; i += 256) {
    sWs[i] = Ws2[i];
    int co = i >> 5, cp = i & 31; sWpT[i] = Wp2[cp*32 + co];
  }
  if (tid < 32) { sbp[tid] = bp2[tid]; lsum[tid]=0.f; lsq[tid]=0.f; }
  if (tid < 16) { sa1[tid] = coef[C_P1+tid]; sc1[tid] = coef[C_P1+16+tid]; }
  __syncthreads();
  int gp = blockIdx.x*16 + (tid >> 4);
  int k  = tid & 15;
  int b = gp >> 15, n = gp & (NPTS-1);
  const float* cb = coords + (size_t)b*(NPTS*3);
  int j = idx[(size_t)gp*KK + k];
  float cx = cb[n*3], cy = cb[n*3+1], cz = cb[n*3+2];
  float px = cb[j*3], py = cb[j*3+1], pz = cb[j*3+2];
  float cat[10] = {cx,cy,cz,px,py,pz,cx-px,cy-py,cz-pz,1.f};
  float x[32];
#pragma unroll
  for (int co = 0; co < 16; ++co) {
    float a = sbl[co];
#pragma unroll
    for (int d0 = 0; d0 < 10; ++d0) a += cat[d0]*sWl[co*10+d0];
    x[co] = a > 0.f ? a : 0.f;
  }
  {
    const float4* xp = (const float4*)(t2ws + (size_t)gp*16);
    float4 u0 = xp[0], u1 = xp[1], u2 = xp[2], u3 = xp[3];
    float xv[16] = {u0.x,u0.y,u0.z,u0.w, u1.x,u1.y,u1.z,u1.w,
                    u2.x,u2.y,u2.z,u2.w, u3.x,u3.y,u3.z,u3.w};
#pragma unroll
    for (int c = 0; c < 16; ++c) {
      float v = xv[c]*sa1[c] + sc1[c];
      x[16+c] = v > 0.f ? v : 0.f;
    }
  }
  float tacc0 = sbp[k], tacc1 = sbp[k+16];
#pragma unroll
  for (int co = 0; co < 32; ++co) {
    float s = 0.f;
#pragma unroll
    for (int ci = 0; ci < 32; ++ci) s += x[ci]*sWs[co*32+ci];
    float m = s;
#pragma unroll
    for (int msk = 8; msk > 0; msk >>= 1) m = fmaxf(m, __shfl_xor(m, msk, 16));
    float e = __expf(s - m);
    float se = e;
#pragma unroll
    for (int msk = 8; msk > 0; msk >>= 1) se += __shfl_xor(se, msk, 16);
    float w = e/se;
    float fv = w*x[co];
#pragma unroll
    for (int msk = 8; msk > 0; msk >>= 1) fv += __shfl_xor(fv, msk, 16);
    tacc0 += fv*sWpT[co*32+k];
    tacc1 += fv*sWpT[co*32+k+16];
  }
  t4[(size_t)gp*32 + k]      = tacc0;
  t4[(size_t)gp*32 + k + 16] = tacc1;
  atomicAdd(&lsum[k], tacc0);      atomicAdd(&lsq[k], tacc0*tacc0);
  atomicAdd(&lsum[k+16], tacc1);   atomicAdd(&lsq[k+16], tacc1*tacc1);
  __syncthreads();
  if (tid < 32) { atomicAdd(&stats[S_P2+tid], lsum[tid]); atomicAdd(&stats[S_P2+32+tid], lsq[tid]); }
}

// ---------------- final: mlp2 + BN'd shortcut + leaky 0.01 ----------------
__global__ void k_final(const float* __restrict__ t4ws, const float* __restrict__ features,
                        const float* __restrict__ W2, const float* __restrict__ b2,
                        const float* __restrict__ Wsc, const float* __restrict__ bsc,
                        const float* __restrict__ coef, float* __restrict__ out) {
  __shared__ float sW2[2048], sb2[64], sWscF[512], sbscF[64], sa[32], scc[32];
  int tid = threadIdx.x;
  for (int i = tid; i < 2048; i += 256) sW2[i] = W2[i];
  if (tid < 64) sb2[tid] = b2[tid];
  for (int i = tid; i < 512; i += 256) { int c2 = i >> 3; sWscF[i] = Wsc[i]*coef[C_SC + c2]; }
  if (tid < 64) sbscF[tid] = bsc[tid]*coef[C_SC+tid] + coef[C_SC+64+tid];
  if (tid < 32) { sa[tid] = coef[C_P2+tid]; scc[tid] = coef[C_P2+32+tid]; }
  __syncthreads();
  int q = blockIdx.x*256 + tid;
  int b = q >> 15, n = q & (NPTS-1);
  float x3[32];
  const float4* tp = (const float4*)(t4ws + (size_t)q*32);
#pragma unroll
  for (int i = 0; i < 8; ++i) {
    float4 u = tp[i];
    float v0 = u.x*sa[4*i+0] + scc[4*i+0];
    float v1 = u.y*sa[4*i+1] + scc[4*i+1];
    float v2 = u.z*sa[4*i+2] + scc[4*i+2];
    float v3 = u.w*sa[4*i+3] + scc[4*i+3];
    x3[4*i+0] = v0 > 0.f ? v0 : 0.f;
    x3[4*i+1] = v1 > 0.f ? v1 : 0.f;
    x3[4*i+2] = v2 > 0.f ? v2 : 0.f;
    x3[4*i+3] = v3 > 0.f ? v3 : 0.f;
  }
  float f[8];
#pragma unroll
  for (int c = 0; c < 8; ++c) f[c] = features[((size_t)b*8+c)*NPTS + n];
  for (int c2 = 0; c2 < 64; ++c2) {
    float acc = sb2[c2];
#pragma unroll
    for (int co = 0; co < 32; ++co) acc += x3[co]*sW2[c2*32+co];
    float sv = sbscF[c2];
#pragma unroll
    for (int c = 0; c < 8; ++c) sv += f[c]*sWscF[c2*8+c];
    float o = acc + sv;
    out[((size_t)b*64 + c2)*NPTS + n] = o > 0.f ? o : 0.01f*o;
  }
}

extern "C" void kernel_launch(void* const* d_in, const int* in_sizes, int n_in,
                              void* d_out, int out_size, void* d_ws, size_t ws_size,
                              hipStream_t stream) {
  const float* coords   = (const float*)d_in[0];
  const float* features = (const float*)d_in[1];
  const float* W1  = (const float*)d_in[2];
  const float* b1  = (const float*)d_in[3];
  const float* Wl1 = (const float*)d_in[4];
  const float* bl1 = (const float*)d_in[5];
  const float* gl1 = (const float*)d_in[6];
  const float* bl1b= (const float*)d_in[7];
  const float* Ws1 = (const float*)d_in[8];
  const float* Wp1 = (const float*)d_in[9];
  const float* bp1 = (const float*)d_in[10];
  const float* gp1 = (const float*)d_in[11];
  const float* bp1b= (const float*)d_in[12];
  const float* Wl2 = (const float*)d_in[13];
  const float* bl2 = (const float*)d_in[14];
  const float* gl2 = (const float*)d_in[15];
  const float* bl2b= (const float*)d_in[16];
  const float* Ws2 = (const float*)d_in[17];
  const float* Wp2 = (const float*)d_in[18];
  const float* bp2 = (const float*)d_in[19];
  const float* gp2 = (const float*)d_in[20];
  const float* bp2b= (const float*)d_in[21];
  const float* W2  = (const float*)d_in[22];
  const float* b2  = (const float*)d_in[23];
  const float* Wsc = (const float*)d_in[24];
  const float* bsc = (const float*)d_in[25];
  const float* gsc = (const float*)d_in[26];
  const float* bscb= (const float*)d_in[27];

  float* wsF  = (float*)d_ws;
  int*   wsI  = (int*)d_ws;
  int*   idxp = wsI;
  float* x1p  = wsF + WS_X1;
  float* t2p  = wsF + WS_T2;
  float* t4p  = wsF + WS_T4;
  float* stat = wsF + WS_STAT;
  float* coef = wsF + WS_COEF;
  int*   gcnt = wsI + WS_GCNT;
  int*   gsta = wsI + WS_GSTART;
  int*   gcel = wsI + WS_CELLID;
  int*   gids = wsI + WS_GIDS;
  unsigned int* bbox = (unsigned int*)(wsI + WS_BBOX);
  int*   gtot = wsI + WS_GTOT;
  float* outp = (float*)d_out;

  hipLaunchKernelGGL(k_zero_all, dim3((2*G3)/256), dim3(256), 0, stream, stat, gcnt, bbox, gtot);
  hipLaunchKernelGGL(k_bbox,    dim3(NQ/256), dim3(256), 0, stream, coords, bbox);
  hipLaunchKernelGGL(k_bin,     dim3(NQ/256), dim3(256), 0, stream, coords, bbox, gcel, gcnt);
  hipLaunchKernelGGL(k_alloc,   dim3((2*G3)/2048), dim3(256), 0, stream, gcnt, gsta, gtot);
  hipLaunchKernelGGL(k_scatter, dim3(NQ/256), dim3(256), 0, stream, gcel, gsta, gids);
  hipLaunchKernelGGL(k_knn_grid,dim3(NQ/256), dim3(256), 0, stream,
                     coords, gcnt, gsta, gids, bbox, idxp);
  hipLaunchKernelGGL(k_mlp1, dim3(NQ/256), dim3(256), 0, stream,
                     features, W1, b1, Wsc, bsc, x1p, stat);
  hipLaunchKernelGGL(k_lsestats, dim3((NQ*KK)/256), dim3(256), 0, stream,
                     coords, idxp, Wl1, bl1, Wl2, bl2, stat);
  hipLaunchKernelGGL(k_bnfin, dim3(1), dim3(64), 0, stream, stat, coef, gl1, bl1b,
                     S_L1, C_L1, 16, 1.f/(float)((size_t)NQ*KK));
  hipLaunchKernelGGL(k_bnfin, dim3(1), dim3(64), 0, stream, stat, coef, gl2, bl2b,
                     S_L2, C_L2, 16, 1.f/(float)((size_t)NQ*KK));
  hipLaunchKernelGGL(k_bnfin, dim3(1), dim3(64), 0, stream, stat, coef, gsc, bscb,
                     S_SC, C_SC, 64, 1.f/(float)NQ);
  hipLaunchKernelGGL(k_att1, dim3(NQ/16), dim3(256), 0, stream,
                     coords, idxp, x1p, Wl1, bl1, Ws1, Wp1, bp1, coef, t2p, stat);
  hipLaunchKernelGGL(k_bnfin, dim3(1), dim3(64), 0, stream, stat, coef, gp1, bp1b,
                     S_P1, C_P1, 16, 1.f/(float)NQ);
  hipLaunchKernelGGL(k_att2, dim3(NQ/16), dim3(256), 0, stream,
                     coords, idxp, t2p, Wl2, bl2, Ws2, Wp2, bp2, coef, t4p, stat);
  hipLaunchKernelGGL(k_bnfin, dim3(1), dim3(64), 0, stream, stat, coef, gp2, bp2b,
                     S_P2, C_P2, 32, 1.f/(float)NQ);
  hipLaunchKernelGGL(k_final, dim3(NQ/256), dim3(256), 0, stream,
                     t4p, features, W2, b2, Wsc, bsc, coef, outp);
}

// Round 3
// 4188.762 us; speedup vs baseline: 1.1434x; 1.1434x over previous
//
#include <hip/hip_runtime.h>
#include <math.h>

#define NPTS  32768
#define NB    2
#define NQ    (NB*NPTS)
#define KK    16
#define EPS   1e-6f
#define G     16
#define G3    (G*G*G)
#define HB    2048
#define SLOP  0.05f

// stats / coef element offsets
#define S_L1 0
#define S_L2 32
#define S_P1 64
#define S_P2 96
#define S_SC 160
#define C_L1 0
#define C_L2 32
#define C_P1 64
#define C_P2 96
#define C_SC 160

// workspace element offsets (4-byte units)
#define WS_X1     (NQ*16)
#define WS_T2     (NQ*32)
#define WS_T4     (NQ*48)
#define WS_STAT   (NQ*80)
#define WS_COEF   (WS_STAT + 512)
#define WS_GCNT   (WS_STAT + 1024)
#define WS_GSTART (WS_GCNT + 2*G3)
#define WS_CELLID (WS_GSTART + 2*G3)
#define WS_SORTID (WS_CELLID + NQ)
#define WS_CSORT  (WS_SORTID + NQ)      /* float4 x NQ (16B-aligned) */
#define WS_BBOX   (WS_CSORT + 4*NQ)
#define WS_HIST   (WS_BBOX + 16)
#define WS_EDGE   (WS_HIST + 6*HB)

__device__ __forceinline__ float wred64(float v) {
#pragma unroll
  for (int m = 32; m > 0; m >>= 1) v += __shfl_xor(v, m, 64);
  return v;
}

// order-preserving float <-> uint encoding for atomic min/max
__device__ __forceinline__ unsigned int encf(float f) {
  unsigned int u = __float_as_uint(f);
  return (u & 0x80000000u) ? ~u : (u | 0x80000000u);
}
__device__ __forceinline__ float decf(unsigned int u) {
  return (u & 0x80000000u) ? __uint_as_float(u & 0x7fffffffu) : __uint_as_float(~u);
}

// 4-step binary search over G=16 quantile edges; e[0] <= x guaranteed
__device__ __forceinline__ int bs16(const float* e, float x) {
  int c = (x >= e[8]) ? 8 : 0;
  c += (x >= e[c+4]) ? 4 : 0;
  c += (x >= e[c+2]) ? 2 : 0;
  c += (x >= e[c+1]) ? 1 : 0;
  return c;
}

// ---------------- zero stats + counters + hist + bbox ----------------
__global__ void k_zero_all(float* __restrict__ stats, int* __restrict__ gcnt,
                           int* __restrict__ hist, unsigned int* __restrict__ bbox) {
  int i = blockIdx.x*256 + threadIdx.x;       // grid covers 12288
  if (i < 2*G3) gcnt[i] = 0;
  if (i < 6*HB) hist[i] = 0;
  if (i < 320)  stats[i] = 0.f;
  if (i < 12)   bbox[i] = ((i % 6) < 3) ? 0xFFFFFFFFu : 0u;
}

// ---------------- per-batch exact bounding box ----------------
__global__ void k_bbox(const float* __restrict__ coords, unsigned int* __restrict__ bbox) {
  __shared__ unsigned int rmn[3][4], rmx[3][4];
  int tid = threadIdx.x;
  int t = blockIdx.x*256 + tid;
  int b = t >> 15, n = t & (NPTS-1);
  const float* cb = coords + (size_t)b*(NPTS*3);
  unsigned int e[3] = { encf(cb[n*3+0]), encf(cb[n*3+1]), encf(cb[n*3+2]) };
  unsigned int mn[3] = { e[0], e[1], e[2] }, mx[3] = { e[0], e[1], e[2] };
#pragma unroll
  for (int s = 32; s > 0; s >>= 1) {
#pragma unroll
    for (int a = 0; a < 3; ++a) {
      unsigned int o1 = (unsigned int)__shfl_xor((int)mn[a], s, 64);
      unsigned int o2 = (unsigned int)__shfl_xor((int)mx[a], s, 64);
      mn[a] = mn[a] < o1 ? mn[a] : o1;
      mx[a] = mx[a] > o2 ? mx[a] : o2;
    }
  }
  int wave = tid >> 6, lane = tid & 63;
  if (lane == 0) {
#pragma unroll
    for (int a = 0; a < 3; ++a) { rmn[a][wave] = mn[a]; rmx[a][wave] = mx[a]; }
  }
  __syncthreads();
  if (tid < 3) {
    unsigned int a0 = min(min(rmn[tid][0], rmn[tid][1]), min(rmn[tid][2], rmn[tid][3]));
    unsigned int A0 = max(max(rmx[tid][0], rmx[tid][1]), max(rmx[tid][2], rmx[tid][3]));
    atomicMin(&bbox[blockIdx.x >= (NQ/256)/2 ? 6+tid : tid], a0);
    atomicMax(&bbox[(blockIdx.x >= (NQ/256)/2 ? 6+tid : tid) + 3], A0);
  }
}

// ---------------- per-axis fine histogram ----------------
__global__ void k_hist(const float* __restrict__ coords, const unsigned int* __restrict__ bbox,
                       int* __restrict__ hist) {
  int t = blockIdx.x*256 + threadIdx.x;
  int b = t >> 15, n = t & (NPTS-1);
  const float* cb = coords + (size_t)b*(NPTS*3);
#pragma unroll
  for (int a = 0; a < 3; ++a) {
    float l = decf(bbox[b*6+a]), h = decf(bbox[b*6+3+a]);
    float ex = (h - l)*(1.f + 4e-7f) + 1e-30f;
    float inv = (float)HB/ex;
    int bin = (int)((cb[n*3+a] - l)*inv);
    bin = min(HB-1, max(0, bin));
    atomicAdd(&hist[(b*3+a)*HB + bin], 1);
  }
}

// ---------------- equal-frequency edges from histogram cdf ----------------
__global__ void k_edges(const int* __restrict__ hist, const unsigned int* __restrict__ bbox,
                        float* __restrict__ edges) {
  __shared__ int part[256];
  int p = blockIdx.x;                 // pair = b*3 + a, 6 blocks
  int b = p/3, a = p - b*3;
  int tid = threadIdx.x;
  const int* h = hist + p*HB;
  int v[8]; int s = 0;
#pragma unroll
  for (int i = 0; i < 8; ++i) { v[i] = h[tid*8 + i]; s += v[i]; }
  part[tid] = s;
  __syncthreads();
  for (int off = 1; off < 256; off <<= 1) {
    int x = part[tid];
    int y = (tid >= off) ? part[tid-off] : 0;
    __syncthreads();
    part[tid] = x + y;
    __syncthreads();
  }
  float l = decf(bbox[b*6+a]), hi = decf(bbox[b*6+3+a]);
  float ex = (hi - l)*(1.f + 4e-7f) + 1e-30f;
  float bw = ex*(1.f/(float)HB);
  int c = part[tid] - s;              // exclusive base
#pragma unroll
  for (int i = 0; i < 8; ++i) {
    int lo_c = c; c += v[i];
#pragma unroll
    for (int g = 1; g < G; ++g) {
      int tq = g*(NPTS/G);
      if (lo_c < tq && c >= tq) edges[p*(G+1) + g] = l + bw*(float)(tid*8 + i + 1);
    }
  }
  if (tid == 0) { edges[p*(G+1)] = l; edges[p*(G+1) + G] = hi + fabsf(hi)*1e-6f + 1e-20f; }
}

// ---------------- bin points into quantile cells ----------------
__global__ void k_bin(const float* __restrict__ coords, const float* __restrict__ edges,
                      int* __restrict__ cellid, int* __restrict__ gcnt) {
  __shared__ float se[3][G+1];
  int tid = threadIdx.x;
  int t = blockIdx.x*256 + tid;
  int b = t >> 15, n = t & (NPTS-1);
  if (tid < 3*(G+1)) se[tid/(G+1)][tid%(G+1)] = edges[b*3*(G+1) + tid];
  __syncthreads();
  const float* cb = coords + (size_t)b*(NPTS*3);
  int c0 = bs16(se[0], cb[n*3+0]);
  int c1 = bs16(se[1], cb[n*3+1]);
  int c2 = bs16(se[2], cb[n*3+2]);
  int cid = b*G3 + (c2*G + c1)*G + c0;
  cellid[t] = cid;
  atomicAdd(&gcnt[cid], 1);
}

// ---------------- deterministic global scan over all 8192 cells ----------------
__global__ void k_alloc(const int* __restrict__ gcnt, int* __restrict__ gstart) {
  __shared__ int part[1024];
  int tid = threadIdx.x;
  int v[8]; int s = 0;
#pragma unroll
  for (int i = 0; i < 8; ++i) { v[i] = gcnt[tid*8 + i]; s += v[i]; }
  part[tid] = s;
  __syncthreads();
  for (int off = 1; off < 1024; off <<= 1) {
    int x = part[tid];
    int y = (tid >= off) ? part[tid-off] : 0;
    __syncthreads();
    part[tid] = x + y;
    __syncthreads();
  }
  int base = part[tid] - s;
#pragma unroll
  for (int i = 0; i < 8; ++i) { gstart[tid*8 + i] = base; base += v[i]; }
}

// ---------------- scatter: packed float4 + original id, cell-sorted ----------------
__global__ void k_scatter(const float* __restrict__ coords, const int* __restrict__ cellid,
                          int* __restrict__ gstart, float4* __restrict__ csort,
                          int* __restrict__ sortid) {
  int t = blockIdx.x*256 + threadIdx.x;
  int b = t >> 15, n = t & (NPTS-1);
  const float* cb = coords + (size_t)b*(NPTS*3);
  int cid = cellid[t];
  int pos = atomicAdd(&gstart[cid], 1);     // after kernel: gstart[c] = end
  float x = cb[n*3+0], y = cb[n*3+1], z = cb[n*3+2];
  csort[pos] = make_float4(x, y, z, x*x + y*y + z*z);
  sortid[pos] = n;
}

// ---------------- exact KNN via expanding shells on the quantile grid ----------------
__launch_bounds__(64)
__global__ void k_knn_grid(const float4* __restrict__ csort, const int* __restrict__ sortid,
                           const int* __restrict__ gcnt, const int* __restrict__ gstart,
                           const float* __restrict__ edges, int* __restrict__ oidx) {
  __shared__ float se[3][G+1];
  int tid = threadIdx.x;
  int t = blockIdx.x*64 + tid;              // global sorted position = query
  int b = t >> 15;
  if (tid < 3*(G+1)) se[tid/(G+1)][tid%(G+1)] = edges[b*3*(G+1) + tid];
  __syncthreads();
  float4 qv = csort[t];
  const float qx = qv.x, qy = qv.y, qz = qv.z, qsq = qv.w;
  const int cx = bs16(se[0], qx), cy = bs16(se[1], qy), cz = bs16(se[2], qz);

  float dl[KK]; int il[KK];
#pragma unroll
  for (int i = 0; i < KK; ++i) { dl[i] = 1e30f; il[i] = 0; }

  auto proc = [&](int x, int y, int z) {
    int c = b*G3 + (z*G + y)*G + x;
    int e = gstart[c], s0 = e - gcnt[c];
    for (int i = s0; i < e; ++i) {
      float4 p = csort[i];
      float d = qsq + p.w - 2.f*(qx*p.x + qy*p.y + qz*p.z);   // == reference formula
      if (d < dl[KK-1]) {                                      // strict <
        float cd = d; int ci = i;
#pragma unroll
        for (int i2 = 0; i2 < KK; ++i2) {
          bool sw = cd < dl[i2];
          float td = dl[i2]; int ti = il[i2];
          dl[i2] = sw ? cd : td; il[i2] = sw ? ci : ti;
          cd = sw ? td : cd;    ci = sw ? ti : ci;
        }
      }
    }
  };

  for (int r = 0; r <= G; ++r) {
    if (r >= 1 && dl[KK-1] < 1e29f) {
      int rm = r - 1;
      float m = 1e30f;
      if (cx-rm > 0)   m = fminf(m, qx - se[0][cx-rm]);
      if (cx+rm < G-1) m = fminf(m, se[0][cx+rm+1] - qx);
      if (cy-rm > 0)   m = fminf(m, qy - se[1][cy-rm]);
      if (cy+rm < G-1) m = fminf(m, se[1][cy+rm+1] - qy);
      if (cz-rm > 0)   m = fminf(m, qz - se[2][cz-rm]);
      if (cz-rm <= 0 && cz+rm >= G-1 && cy-rm <= 0 && cy+rm >= G-1 && cx-rm <= 0 && cx+rm >= G-1) break;
      if (cz+rm < G-1) m = fminf(m, se[2][cz+rm+1] - qz);
      if (m > 0.f && m*m > dl[KK-1] + SLOP) break;
    }
    int zlo = max(cz-r, 0), zhi = min(cz+r, G-1);
    for (int z = zlo; z <= zhi; ++z) {
      bool zf = (z == cz-r) || (z == cz+r);
      int ylo = max(cy-r, 0), yhi = min(cy+r, G-1);
      for (int y = ylo; y <= yhi; ++y) {
        bool yf = (y == cy-r) || (y == cy+r);
        if (zf || yf) {
          int xlo = max(cx-r, 0), xhi = min(cx+r, G-1);
          for (int x = xlo; x <= xhi; ++x) proc(x, y, z);
        } else {
          if (cx-r >= 0)   proc(cx-r, y, z);
          if (cx+r <= G-1) proc(cx+r, y, z);
        }
      }
    }
  }
  int qn = sortid[t];
#pragma unroll
  for (int i = 0; i < KK; ++i) oidx[((size_t)(b*NPTS + qn))*KK + i] = sortid[il[i]];
}

// ---------------- mlp1 (leaky 0.2) + shortcut BN stats ----------------
__global__ void k_mlp1(const float* __restrict__ features,
                       const float* __restrict__ W1, const float* __restrict__ b1,
                       const float* __restrict__ Wsc, const float* __restrict__ bsc,
                       float* __restrict__ x1, float* __restrict__ stats) {
  __shared__ float sW1[128], sb1[16], sWsc[512], sbsc[64];
  int tid = threadIdx.x;
  if (tid < 128) sW1[tid] = W1[tid];
  if (tid < 16)  sb1[tid] = b1[tid];
  if (tid < 64)  sbsc[tid] = bsc[tid];
  for (int i = tid; i < 512; i += 256) sWsc[i] = Wsc[i];
  __syncthreads();
  int q = blockIdx.x*256 + tid;
  int b = q >> 15, n = q & (NPTS-1);
  float f[8];
#pragma unroll
  for (int c = 0; c < 8; ++c) f[c] = features[((size_t)b*8 + c)*NPTS + n];
#pragma unroll
  for (int co = 0; co < 16; ++co) {
    float a = sb1[co];
#pragma unroll
    for (int c = 0; c < 8; ++c) a += f[c]*sW1[co*8+c];
    x1[(size_t)q*16 + co] = a > 0.f ? a : 0.2f*a;
  }
  int lane = tid & 63;
#pragma unroll
  for (int co = 0; co < 64; ++co) {
    float a = sbsc[co];
#pragma unroll
    for (int c = 0; c < 8; ++c) a += f[c]*sWsc[co*8+c];
    float s = wred64(a), ss = wred64(a*a);
    if (lane == 0) { atomicAdd(&stats[S_SC+co], s); atomicAdd(&stats[S_SC+64+co], ss); }
  }
}

// ---------------- BN stats for BOTH LSE geometric encodings ----------------
__global__ void k_lsestats(const float* __restrict__ coords, const int* __restrict__ idx,
                           const float* __restrict__ Wl1, const float* __restrict__ bl1,
                           const float* __restrict__ Wl2, const float* __restrict__ bl2,
                           float* __restrict__ stats) {
  __shared__ float sW1[160], sb1[16], sW2[160], sb2[16];
  __shared__ float red[4][64];
  int tid = threadIdx.x;
  for (int i = tid; i < 160; i += 256) { sW1[i] = Wl1[i]; sW2[i] = Wl2[i]; }
  if (tid < 16) { sb1[tid] = bl1[tid]; sb2[tid] = bl2[tid]; }
  __syncthreads();
  int t = blockIdx.x*256 + tid;         // (b,n,k) flat
  int q = t >> 4;
  int b = q >> 15, n = q & (NPTS-1);
  const float* cb = coords + (size_t)b*(NPTS*3);
  int j = idx[t];
  float cx = cb[n*3], cy = cb[n*3+1], cz = cb[n*3+2];
  float px = cb[j*3], py = cb[j*3+1], pz = cb[j*3+2];
  float cat[10] = {cx,cy,cz,px,py,pz,cx-px,cy-py,cz-pz,1.f};
  int wave = tid >> 6, lane = tid & 63;
#pragma unroll
  for (int co = 0; co < 16; ++co) {
    float a1 = sb1[co], a2 = sb2[co];
#pragma unroll
    for (int d0 = 0; d0 < 10; ++d0) { a1 += cat[d0]*sW1[co*10+d0]; a2 += cat[d0]*sW2[co*10+d0]; }
    float s1 = wred64(a1), q1 = wred64(a1*a1);
    float s2 = wred64(a2), q2 = wred64(a2*a2);
    if (lane == 0) { red[wave][co]=s1; red[wave][16+co]=q1; red[wave][32+co]=s2; red[wave][48+co]=q2; }
  }
  __syncthreads();
  if (tid < 64) {
    float v = red[0][tid] + red[1][tid] + red[2][tid] + red[3][tid];
    int grp = tid >> 4, c = tid & 15;
    int off = (grp == 0) ? (S_L1 + c) : (grp == 1) ? (S_L1 + 16 + c)
            : (grp == 2) ? (S_L2 + c) : (S_L2 + 16 + c);
    atomicAdd(&stats[off], v);
  }
}

// ---------------- BN finalize ----------------
__global__ void k_bnfin(const float* __restrict__ stats, float* __restrict__ coef,
                        const float* __restrict__ gam, const float* __restrict__ bet,
                        int soff, int coff, int nch, float invc) {
  int c = threadIdx.x;
  if (c < nch) {
    float m = stats[soff + c]*invc;
    float v = stats[soff + nch + c]*invc - m*m;
    float a = gam[c]*rsqrtf(v + EPS);
    coef[coff + c] = a;
    coef[coff + nch + c] = bet[c] - m*a;
  }
}

// ---------------- LSE1 + attentive pooling 1 ----------------
__launch_bounds__(256)
__global__ void k_att1(const float* __restrict__ coords, const int* __restrict__ idx,
                       const float* __restrict__ x1ws,
                       const float* __restrict__ Wl1, const float* __restrict__ bl1,
                       const float* __restrict__ Ws1, const float* __restrict__ Wp1,
                       const float* __restrict__ bp1, const float* __restrict__ coef,
                       float* __restrict__ t2, float* __restrict__ stats) {
  __shared__ float sWl[160], sbl[16];
  __shared__ float sWs[1024];
  __shared__ float sWpT[512], sbp[16];
  __shared__ float lsum[16], lsq[16];
  int tid = threadIdx.x;
  for (int i = tid; i < 160; i += 256) { int c = i/10; sWl[i] = Wl1[i]*coef[C_L1 + c]; }
  if (tid < 16) sbl[tid] = bl1[tid]*coef[C_L1+tid] + coef[C_L1+16+tid];
  for (int i = tid; i < 1024; i += 256) sWs[i] = Ws1[i];
  for (int i = tid; i < 512; i += 256) { int co = i >> 4, cp = i & 15; sWpT[i] = Wp1[cp*32 + co]; }
  if (tid < 16) { sbp[tid] = bp1[tid]; lsum[tid] = 0.f; lsq[tid] = 0.f; }
  __syncthreads();
  int gp = blockIdx.x*16 + (tid >> 4);
  int k  = tid & 15;
  int b = gp >> 15, n = gp & (NPTS-1);
  const float* cb = coords + (size_t)b*(NPTS*3);
  int j = idx[(size_t)gp*KK + k];
  float cx = cb[n*3], cy = cb[n*3+1], cz = cb[n*3+2];
  float px = cb[j*3], py = cb[j*3+1], pz = cb[j*3+2];
  float cat[10] = {cx,cy,cz,px,py,pz,cx-px,cy-py,cz-pz,1.f};
  float x[32];
#pragma unroll
  for (int co = 0; co < 16; ++co) {
    float a = sbl[co];
#pragma unroll
    for (int d0 = 0; d0 < 10; ++d0) a += cat[d0]*sWl[co*10+d0];
    x[co] = a > 0.f ? a : 0.f;
  }
  {
    const float4* xp = (const float4*)(x1ws + (size_t)gp*16);
    float4 u0 = xp[0], u1 = xp[1], u2 = xp[2], u3 = xp[3];
    x[16]=u0.x; x[17]=u0.y; x[18]=u0.z; x[19]=u0.w;
    x[20]=u1.x; x[21]=u1.y; x[22]=u1.z; x[23]=u1.w;
    x[24]=u2.x; x[25]=u2.y; x[26]=u2.z; x[27]=u2.w;
    x[28]=u3.x; x[29]=u3.y; x[30]=u3.z; x[31]=u3.w;
  }
  float tacc = sbp[k];
#pragma unroll
  for (int co = 0; co < 32; ++co) {
    float s = 0.f;
#pragma unroll
    for (int ci = 0; ci < 32; ++ci) s += x[ci]*sWs[co*32+ci];
    float m = s;
#pragma unroll
    for (int msk = 8; msk > 0; msk >>= 1) m = fmaxf(m, __shfl_xor(m, msk, 16));
    float e = __expf(s - m);
    float se = e;
#pragma unroll
    for (int msk = 8; msk > 0; msk >>= 1) se += __shfl_xor(se, msk, 16);
    float w = e/se;
    float fv = w*x[co];
#pragma unroll
    for (int msk = 8; msk > 0; msk >>= 1) fv += __shfl_xor(fv, msk, 16);
    tacc += fv*sWpT[co*16+k];
  }
  t2[(size_t)gp*16 + k] = tacc;
  atomicAdd(&lsum[k], tacc);
  atomicAdd(&lsq[k], tacc*tacc);
  __syncthreads();
  if (tid < 16) { atomicAdd(&stats[S_P1+tid], lsum[tid]); atomicAdd(&stats[S_P1+16+tid], lsq[tid]); }
}

// ---------------- LSE2 + attentive pooling 2 ----------------
__launch_bounds__(256)
__global__ void k_att2(const float* __restrict__ coords, const int* __restrict__ idx,
                       const float* __restrict__ t2ws,
                       const float* __restrict__ Wl2, const float* __restrict__ bl2,
                       const float* __restrict__ Ws2, const float* __restrict__ Wp2,
                       const float* __restrict__ bp2, const float* __restrict__ coef,
                       float* __restrict__ t4, float* __restrict__ stats) {
  __shared__ float sWl[160], sbl[16];
  __shared__ float sWs[1024];
  __shared__ float sWpT[1024], sbp[32];
  __shared__ float sa1[16], sc1[16];
  __shared__ float lsum[32], lsq[32];
  int tid = threadIdx.x;
  for (int i = tid; i < 160; i += 256) { int c = i/10; sWl[i] = Wl2[i]*coef[C_L2 + c]; }
  if (tid < 16) sbl[tid] = bl2[tid]*coef[C_L2+tid] + coef[C_L2+16+tid];
  for (int i = tid; i < 1024; i += 256) {
    sWs[i] = Ws2[i];
    int co = i >> 5, cp = i & 31; sWpT[i] = Wp2[cp*32 + co];
  }
  if (tid < 32) { sbp[tid] = bp2[tid]; lsum[tid]=0.f; lsq[tid]=0.f; }
  if (tid < 16) { sa1[tid] = coef[C_P1+tid]; sc1[tid] = coef[C_P1+16+tid]; }
  __syncthreads();
  int gp = blockIdx.x*16 + (tid >> 4);
  int k  = tid & 15;
  int b = gp >> 15, n = gp & (NPTS-1);
  const float* cb = coords + (size_t)b*(NPTS*3);
  int j = idx[(size_t)gp*KK + k];
  float cx = cb[n*3], cy = cb[n*3+1], cz = cb[n*3+2];
  float px = cb[j*3], py = cb[j*3+1], pz = cb[j*3+2];
  float cat[10] = {cx,cy,cz,px,py,pz,cx-px,cy-py,cz-pz,1.f};
  float x[32];
#pragma unroll
  for (int co = 0; co < 16; ++co) {
    float a = sbl[co];
#pragma unroll
    for (int d0 = 0; d0 < 10; ++d0) a += cat[d0]*sWl[co*10+d0];
    x[co] = a > 0.f ? a : 0.f;
  }
  {
    const float4* xp = (const float4*)(t2ws + (size_t)gp*16);
    float4 u0 = xp[0], u1 = xp[1], u2 = xp[2], u3 = xp[3];
    float xv[16] = {u0.x,u0.y,u0.z,u0.w, u1.x,u1.y,u1.z,u1.w,
                    u2.x,u2.y,u2.z,u2.w, u3.x,u3.y,u3.z,u3.w};
#pragma unroll
    for (int c = 0; c < 16; ++c) {
      float v = xv[c]*sa1[c] + sc1[c];
      x[16+c] = v > 0.f ? v : 0.f;
    }
  }
  float tacc0 = sbp[k], tacc1 = sbp[k+16];
#pragma unroll
  for (int co = 0; co < 32; ++co) {
    float s = 0.f;
#pragma unroll
    for (int ci = 0; ci < 32; ++ci) s += x[ci]*sWs[co*32+ci];
    float m = s;
#pragma unroll
    for (int msk = 8; msk > 0; msk >>= 1) m = fmaxf(m, __shfl_xor(m, msk, 16));
    float e = __expf(s - m);
    float se = e;
#pragma unroll
    for (int msk = 8; msk > 0; msk >>= 1) se += __shfl_xor(se, msk, 16);
    float w = e/se;
    float fv = w*x[co];
#pragma unroll
    for (int msk = 8; msk > 0; msk >>= 1) fv += __shfl_xor(fv, msk, 16);
    tacc0 += fv*sWpT[co*32+k];
    tacc1 += fv*sWpT[co*32+k+16];
  }
  t4[(size_t)gp*32 + k]      = tacc0;
  t4[(size_t)gp*32 + k + 16] = tacc1;
  atomicAdd(&lsum[k], tacc0);      atomicAdd(&lsq[k], tacc0*tacc0);
  atomicAdd(&lsum[k+16], tacc1);   atomicAdd(&lsq[k+16], tacc1*tacc1);
  __syncthreads();
  if (tid < 32) { atomicAdd(&stats[S_P2+tid], lsum[tid]); atomicAdd(&stats[S_P2+32+tid], lsq[tid]); }
}

// ---------------- final: mlp2 + BN'd shortcut + leaky 0.01 ----------------
__global__ void k_final(const float* __restrict__ t4ws, const float* __restrict__ features,
                        const float* __restrict__ W2, const float* __restrict__ b2,
                        const float* __restrict__ Wsc, const float* __restrict__ bsc,
                        const float* __restrict__ coef, float* __restrict__ out) {
  __shared__ float sW2[2048], sb2[64], sWscF[512], sbscF[64], sa[32], scc[32];
  int tid = threadIdx.x;
  for (int i = tid; i < 2048; i += 256) sW2[i] = W2[i];
  if (tid < 64) sb2[tid] = b2[tid];
  for (int i = tid; i < 512; i += 256) { int c2 = i >> 3; sWscF[i] = Wsc[i]*coef[C_SC + c2]; }
  if (tid < 64) sbscF[tid] = bsc[tid]*coef[C_SC+tid] + coef[C_SC+64+tid];
  if (tid < 32) { sa[tid] = coef[C_P2+tid]; scc[tid] = coef[C_P2+32+tid]; }
  __syncthreads();
  int q = blockIdx.x*256 + tid;
  int b = q >> 15, n = q & (NPTS-1);
  float x3[32];
  const float4* tp = (const float4*)(t4ws + (size_t)q*32);
#pragma unroll
  for (int i = 0; i < 8; ++i) {
    float4 u = tp[i];
    float v0 = u.x*sa[4*i+0] + scc[4*i+0];
    float v1 = u.y*sa[4*i+1] + scc[4*i+1];
    float v2 = u.z*sa[4*i+2] + scc[4*i+2];
    float v3 = u.w*sa[4*i+3] + scc[4*i+3];
    x3[4*i+0] = v0 > 0.f ? v0 : 0.f;
    x3[4*i+1] = v1 > 0.f ? v1 : 0.f;
    x3[4*i+2] = v2 > 0.f ? v2 : 0.f;
    x3[4*i+3] = v3 > 0.f ? v3 : 0.f;
  }
  float f[8];
#pragma unroll
  for (int c = 0; c < 8; ++c) f[c] = features[((size_t)b*8+c)*NPTS + n];
  for (int c2 = 0; c2 < 64; ++c2) {
    float acc = sb2[c2];
#pragma unroll
    for (int co = 0; co < 32; ++co) acc += x3[co]*sW2[c2*32+co];
    float sv = sbscF[c2];
#pragma unroll
    for (int c = 0; c < 8; ++c) sv += f[c]*sWscF[c2*8+c];
    float o = acc + sv;
    out[((size_t)b*64 + c2)*NPTS + n] = o > 0.f ? o : 0.01f*o;
  }
}

extern "C" void kernel_launch(void* const* d_in, const int* in_sizes, int n_in,
                              void* d_out, int out_size, void* d_ws, size_t ws_size,
                              hipStream_t stream) {
  const float* coords   = (const float*)d_in[0];
  const float* features = (const float*)d_in[1];
  const float* W1  = (const float*)d_in[2];
  const float* b1  = (const float*)d_in[3];
  const float* Wl1 = (const float*)d_in[4];
  const float* bl1 = (const float*)d_in[5];
  const float* gl1 = (const float*)d_in[6];
  const float* bl1b= (const float*)d_in[7];
  const float* Ws1 = (const float*)d_in[8];
  const float* Wp1 = (const float*)d_in[9];
  const float* bp1 = (const float*)d_in[10];
  const float* gp1 = (const float*)d_in[11];
  const float* bp1b= (const float*)d_in[12];
  const float* Wl2 = (const float*)d_in[13];
  const float* bl2 = (const float*)d_in[14];
  const float* gl2 = (const float*)d_in[15];
  const float* bl2b= (const float*)d_in[16];
  const float* Ws2 = (const float*)d_in[17];
  const float* Wp2 = (const float*)d_in[18];
  const float* bp2 = (const float*)d_in[19];
  const float* gp2 = (const float*)d_in[20];
  const float* bp2b= (const float*)d_in[21];
  const float* W2  = (const float*)d_in[22];
  const float* b2  = (const float*)d_in[23];
  const float* Wsc = (const float*)d_in[24];
  const float* bsc = (const float*)d_in[25];
  const float* gsc = (const float*)d_in[26];
  const float* bscb= (const float*)d_in[27];

  float* wsF  = (float*)d_ws;
  int*   wsI  = (int*)d_ws;
  int*   idxp = wsI;
  float* x1p  = wsF + WS_X1;
  float* t2p  = wsF + WS_T2;
  float* t4p  = wsF + WS_T4;
  float* stat = wsF + WS_STAT;
  float* coef = wsF + WS_COEF;
  int*   gcnt = wsI + WS_GCNT;
  int*   gsta = wsI + WS_GSTART;
  int*   gcel = wsI + WS_CELLID;
  int*   sid  = wsI + WS_SORTID;
  float4* csrt = (float4*)(wsF + WS_CSORT);
  unsigned int* bbox = (unsigned int*)(wsI + WS_BBOX);
  int*   hist = wsI + WS_HIST;
  float* edge = wsF + WS_EDGE;
  float* outp = (float*)d_out;

  hipLaunchKernelGGL(k_zero_all, dim3(48), dim3(256), 0, stream, stat, gcnt, hist, bbox);
  hipLaunchKernelGGL(k_bbox,    dim3(NQ/256), dim3(256), 0, stream, coords, bbox);
  hipLaunchKernelGGL(k_hist,    dim3(NQ/256), dim3(256), 0, stream, coords, bbox, hist);
  hipLaunchKernelGGL(k_edges,   dim3(6), dim3(256), 0, stream, hist, bbox, edge);
  hipLaunchKernelGGL(k_bin,     dim3(NQ/256), dim3(256), 0, stream, coords, edge, gcel, gcnt);
  hipLaunchKernelGGL(k_alloc,   dim3(1), dim3(1024), 0, stream, gcnt, gsta);
  hipLaunchKernelGGL(k_scatter, dim3(NQ/256), dim3(256), 0, stream, coords, gcel, gsta, csrt, sid);
  hipLaunchKernelGGL(k_knn_grid,dim3(NQ/64), dim3(64), 0, stream,
                     csrt, sid, gcnt, gsta, edge, idxp);
  hipLaunchKernelGGL(k_mlp1, dim3(NQ/256), dim3(256), 0, stream,
                     features, W1, b1, Wsc, bsc, x1p, stat);
  hipLaunchKernelGGL(k_lsestats, dim3((NQ*KK)/256), dim3(256), 0, stream,
                     coords, idxp, Wl1, bl1, Wl2, bl2, stat);
  hipLaunchKernelGGL(k_bnfin, dim3(1), dim3(64), 0, stream, stat, coef, gl1, bl1b,
                     S_L1, C_L1, 16, 1.f/(float)((size_t)NQ*KK));
  hipLaunchKernelGGL(k_bnfin, dim3(1), dim3(64), 0, stream, stat, coef, gl2, bl2b,
                     S_L2, C_L2, 16, 1.f/(float)((size_t)NQ*KK));
  hipLaunchKernelGGL(k_bnfin, dim3(1), dim3(64), 0, stream, stat, coef, gsc, bscb,
                     S_SC, C_SC, 64, 1.f/(float)NQ);
  hipLaunchKernelGGL(k_att1, dim3(NQ/16), dim3(256), 0, stream,
                     coords, idxp, x1p, Wl1, bl1, Ws1, Wp1, bp1, coef, t2p, stat);
  hipLaunchKernelGGL(k_bnfin, dim3(1), dim3(64), 0, stream, stat, coef, gp1, bp1b,
                     S_P1, C_P1, 16, 1.f/(float)NQ);
  hipLaunchKernelGGL(k_att2, dim3(NQ/16), dim3(256), 0, stream,
                     coords, idxp, t2p, Wl2, bl2, Ws2, Wp2, bp2, coef, t4p, stat);
  hipLaunchKernelGGL(k_bnfin, dim3(1), dim3(64), 0, stream, stat, coef, gp2, bp2b,
                     S_P2, C_P2, 32, 1.f/(float)NQ);
  hipLaunchKernelGGL(k_final, dim3(NQ/256), dim3(256), 0, stream,
                     t4p, features, W2, b2, Wsc, bsc, coef, outp);
}

// Round 4
// 2179.320 us; speedup vs baseline: 2.1977x; 1.9221x over previous
//
#include <hip/hip_runtime.h>
#include <math.h>

#define NPTS  32768
#define NB    2
#define NQ    (NB*NPTS)
#define KK    16
#define EPS   1e-6f
#define G     16
#define G3    (G*G*G)
#define HB    2048
#define SLOP  0.05f
#define LPQ   4

// stats / coef element offsets
#define S_L1 0
#define S_L2 32
#define S_P1 64
#define S_P2 96
#define S_SC 160
#define C_L1 0
#define C_L2 32
#define C_P1 64
#define C_P2 96
#define C_SC 160

// workspace element offsets (4-byte units)
#define WS_X1     (NQ*16)
#define WS_T2     (NQ*32)
#define WS_T4     (NQ*48)
#define WS_STAT   (NQ*80)
#define WS_COEF   (WS_STAT + 512)
#define WS_GCNT   (WS_STAT + 1024)
#define WS_GSTART (WS_GCNT + 2*G3)
#define WS_CELLID (WS_GSTART + 2*G3)
#define WS_SORTID (WS_CELLID + NQ)
#define WS_CSORT  (WS_SORTID + NQ)      /* float4 x NQ (16B-aligned) */
#define WS_BBOX   (WS_CSORT + 4*NQ)
#define WS_HIST   (WS_BBOX + 16)
#define WS_EDGE   (WS_HIST + 6*HB)
#define WS_STARTS WS_HIST               /* starts aliases hist (dead after k_edges) */

__device__ __forceinline__ float wred64(float v) {
#pragma unroll
  for (int m = 32; m > 0; m >>= 1) v += __shfl_xor(v, m, 64);
  return v;
}

// order-preserving float <-> uint encoding for atomic min/max
__device__ __forceinline__ unsigned int encf(float f) {
  unsigned int u = __float_as_uint(f);
  return (u & 0x80000000u) ? ~u : (u | 0x80000000u);
}
__device__ __forceinline__ float decf(unsigned int u) {
  return (u & 0x80000000u) ? __uint_as_float(u & 0x7fffffffu) : __uint_as_float(~u);
}

// 4-step binary search over G=16 quantile edges; e[0] <= x guaranteed
__device__ __forceinline__ int bs16(const float* e, float x) {
  int c = (x >= e[8]) ? 8 : 0;
  c += (x >= e[c+4]) ? 4 : 0;
  c += (x >= e[c+2]) ? 2 : 0;
  c += (x >= e[c+1]) ? 1 : 0;
  return c;
}

// ---------------- zero stats + counters + hist + bbox ----------------
__global__ void k_zero_all(float* __restrict__ stats, int* __restrict__ gcnt,
                           int* __restrict__ hist, unsigned int* __restrict__ bbox) {
  int i = blockIdx.x*256 + threadIdx.x;       // grid covers 12288
  if (i < 2*G3) gcnt[i] = 0;
  if (i < 6*HB) hist[i] = 0;
  if (i < 320)  stats[i] = 0.f;
  if (i < 12)   bbox[i] = ((i % 6) < 3) ? 0xFFFFFFFFu : 0u;
}

// ---------------- per-batch exact bounding box ----------------
__global__ void k_bbox(const float* __restrict__ coords, unsigned int* __restrict__ bbox) {
  __shared__ unsigned int rmn[3][4], rmx[3][4];
  int tid = threadIdx.x;
  int t = blockIdx.x*256 + tid;
  int b = t >> 15, n = t & (NPTS-1);
  const float* cb = coords + (size_t)b*(NPTS*3);
  unsigned int e[3] = { encf(cb[n*3+0]), encf(cb[n*3+1]), encf(cb[n*3+2]) };
  unsigned int mn[3] = { e[0], e[1], e[2] }, mx[3] = { e[0], e[1], e[2] };
#pragma unroll
  for (int s = 32; s > 0; s >>= 1) {
#pragma unroll
    for (int a = 0; a < 3; ++a) {
      unsigned int o1 = (unsigned int)__shfl_xor((int)mn[a], s, 64);
      unsigned int o2 = (unsigned int)__shfl_xor((int)mx[a], s, 64);
      mn[a] = mn[a] < o1 ? mn[a] : o1;
      mx[a] = mx[a] > o2 ? mx[a] : o2;
    }
  }
  int wave = tid >> 6, lane = tid & 63;
  if (lane == 0) {
#pragma unroll
    for (int a = 0; a < 3; ++a) { rmn[a][wave] = mn[a]; rmx[a][wave] = mx[a]; }
  }
  __syncthreads();
  if (tid < 3) {
    unsigned int a0 = min(min(rmn[tid][0], rmn[tid][1]), min(rmn[tid][2], rmn[tid][3]));
    unsigned int A0 = max(max(rmx[tid][0], rmx[tid][1]), max(rmx[tid][2], rmx[tid][3]));
    atomicMin(&bbox[b*6 + tid], a0);
    atomicMax(&bbox[b*6 + 3 + tid], A0);
  }
}

// ---------------- per-axis fine histogram ----------------
__global__ void k_hist(const float* __restrict__ coords, const unsigned int* __restrict__ bbox,
                       int* __restrict__ hist) {
  int t = blockIdx.x*256 + threadIdx.x;
  int b = t >> 15, n = t & (NPTS-1);
  const float* cb = coords + (size_t)b*(NPTS*3);
#pragma unroll
  for (int a = 0; a < 3; ++a) {
    float l = decf(bbox[b*6+a]), h = decf(bbox[b*6+3+a]);
    float ex = (h - l)*(1.f + 4e-7f) + 1e-30f;
    float inv = (float)HB/ex;
    int bin = (int)((cb[n*3+a] - l)*inv);
    bin = min(HB-1, max(0, bin));
    atomicAdd(&hist[(b*3+a)*HB + bin], 1);
  }
}

// ---------------- equal-frequency edges from histogram cdf ----------------
__global__ void k_edges(const int* __restrict__ hist, const unsigned int* __restrict__ bbox,
                        float* __restrict__ edges) {
  __shared__ int part[256];
  int p = blockIdx.x;                 // pair = b*3 + a, 6 blocks
  int b = p/3, a = p - b*3;
  int tid = threadIdx.x;
  const int* h = hist + p*HB;
  int v[8]; int s = 0;
#pragma unroll
  for (int i = 0; i < 8; ++i) { v[i] = h[tid*8 + i]; s += v[i]; }
  part[tid] = s;
  __syncthreads();
  for (int off = 1; off < 256; off <<= 1) {
    int x = part[tid];
    int y = (tid >= off) ? part[tid-off] : 0;
    __syncthreads();
    part[tid] = x + y;
    __syncthreads();
  }
  float l = decf(bbox[b*6+a]), hi = decf(bbox[b*6+3+a]);
  float ex = (hi - l)*(1.f + 4e-7f) + 1e-30f;
  float bw = ex*(1.f/(float)HB);
  int c = part[tid] - s;              // exclusive base
#pragma unroll
  for (int i = 0; i < 8; ++i) {
    int lo_c = c; c += v[i];
#pragma unroll
    for (int g = 1; g < G; ++g) {
      int tq = g*(NPTS/G);
      if (lo_c < tq && c >= tq) edges[p*(G+1) + g] = l + bw*(float)(tid*8 + i + 1);
    }
  }
  if (tid == 0) { edges[p*(G+1)] = l; edges[p*(G+1) + G] = hi + fabsf(hi)*1e-6f + 1e-20f; }
}

// ---------------- bin points into quantile cells ----------------
__global__ void k_bin(const float* __restrict__ coords, const float* __restrict__ edges,
                      int* __restrict__ cellid, int* __restrict__ gcnt) {
  __shared__ float se[3][G+1];
  int tid = threadIdx.x;
  int t = blockIdx.x*256 + tid;
  int b = t >> 15, n = t & (NPTS-1);
  if (tid < 3*(G+1)) se[tid/(G+1)][tid%(G+1)] = edges[b*3*(G+1) + tid];
  __syncthreads();
  const float* cb = coords + (size_t)b*(NPTS*3);
  int c0 = bs16(se[0], cb[n*3+0]);
  int c1 = bs16(se[1], cb[n*3+1]);
  int c2 = bs16(se[2], cb[n*3+2]);
  int cid = b*G3 + (c2*G + c1)*G + c0;
  cellid[t] = cid;
  atomicAdd(&gcnt[cid], 1);
}

// ---------------- deterministic global scan over all 8192 cells ----------------
// writes gstart (mutated by scatter) AND starts (+sentinel, read by knn)
__global__ void k_alloc(const int* __restrict__ gcnt, int* __restrict__ gstart,
                        int* __restrict__ starts) {
  __shared__ int part[1024];
  int tid = threadIdx.x;
  int v[8]; int s = 0;
#pragma unroll
  for (int i = 0; i < 8; ++i) { v[i] = gcnt[tid*8 + i]; s += v[i]; }
  part[tid] = s;
  __syncthreads();
  for (int off = 1; off < 1024; off <<= 1) {
    int x = part[tid];
    int y = (tid >= off) ? part[tid-off] : 0;
    __syncthreads();
    part[tid] = x + y;
    __syncthreads();
  }
  int base = part[tid] - s;
#pragma unroll
  for (int i = 0; i < 8; ++i) { gstart[tid*8 + i] = base; starts[tid*8 + i] = base; base += v[i]; }
  if (tid == 1023) starts[2*G3] = NQ;
}

// ---------------- scatter: packed float4 + original id, cell-sorted ----------------
__global__ void k_scatter(const float* __restrict__ coords, const int* __restrict__ cellid,
                          int* __restrict__ gstart, float4* __restrict__ csort,
                          int* __restrict__ sortid) {
  int t = blockIdx.x*256 + threadIdx.x;
  int b = t >> 15, n = t & (NPTS-1);
  const float* cb = coords + (size_t)b*(NPTS*3);
  int cid = cellid[t];
  int pos = atomicAdd(&gstart[cid], 1);
  float x = cb[n*3+0], y = cb[n*3+1], z = cb[n*3+2];
  csort[pos] = make_float4(x, y, z, x*x + y*y + z*z);
  sortid[pos] = n;
}

// ---------------- exact KNN: 4 lanes/query, row-contiguous probes ----------------
__launch_bounds__(256)
__global__ void k_knn_grid(const float4* __restrict__ csort, const int* __restrict__ sortid,
                           const int* __restrict__ starts, const float* __restrict__ edges,
                           int* __restrict__ oidx) {
  __shared__ float se[3][G+1];
  int tid = threadIdx.x;
  int t = blockIdx.x*64 + (tid >> 2);       // query = global sorted position
  int sub = tid & 3;                        // lane within 4-lane group
  int b = t >> 15;                          // 64 | 32768 -> uniform per block
  if (tid < 3*(G+1)) se[tid/(G+1)][tid%(G+1)] = edges[b*3*(G+1) + tid];
  __syncthreads();
  float4 qv = csort[t];
  const float qx = qv.x, qy = qv.y, qz = qv.z, qsq = qv.w;
  const int cx = bs16(se[0], qx), cy = bs16(se[1], qy), cz = bs16(se[2], qz);

  float dl[KK]; int il[KK];
#pragma unroll
  for (int i = 0; i < KK; ++i) { dl[i] = 1e30f; il[i] = 0; }

  auto prange = [&](int s0, int e0) {
    for (int i = s0 + sub; i < e0; i += LPQ) {
      float4 p = csort[i];
      float d = qsq + p.w - 2.f*(qx*p.x + qy*p.y + qz*p.z);   // == reference formula
      if (d < dl[KK-1]) {                                      // strict <
        float cd = d; int ci = i;
#pragma unroll
        for (int i2 = 0; i2 < KK; ++i2) {
          bool sw = cd < dl[i2];
          float td = dl[i2]; int ti = il[i2];
          dl[i2] = sw ? cd : td; il[i2] = sw ? ci : ti;
          cd = sw ? td : cd;    ci = sw ? ti : ci;
        }
      }
    }
  };
  auto prow = [&](int y, int z, int xa, int xb) {
    int c0 = b*G3 + (z*G + y)*G + xa;
    prange(starts[c0], starts[c0 + (xb - xa) + 1]);
  };

  for (int r = 0; r <= G; ++r) {
    if (r >= 1) {
      int rm = r - 1;
      if (cx-rm <= 0 && cx+rm >= G-1 && cy-rm <= 0 && cy+rm >= G-1 &&
          cz-rm <= 0 && cz+rm >= G-1) break;                   // searched everything
      // group-wide upper bound on true d16:
      //   L = min over lanes of lane-16th; M = max over lanes of lane-4th
      float m3 = dl[3], m15 = dl[KK-1];
      float M = fmaxf(m3, __shfl_xor(m3, 1, 64)); M = fmaxf(M, __shfl_xor(M, 2, 64));
      float L = fminf(m15, __shfl_xor(m15, 1, 64)); L = fminf(L, __shfl_xor(L, 2, 64));
      float bound = fminf(M, L);
      if (bound < 1e29f) {
        float m = 1e30f;
        if (cx-rm > 0)   m = fminf(m, qx - se[0][cx-rm]);
        if (cx+rm < G-1) m = fminf(m, se[0][cx+rm+1] - qx);
        if (cy-rm > 0)   m = fminf(m, qy - se[1][cy-rm]);
        if (cy+rm < G-1) m = fminf(m, se[1][cy+rm+1] - qy);
        if (cz-rm > 0)   m = fminf(m, qz - se[2][cz-rm]);
        if (cz+rm < G-1) m = fminf(m, se[2][cz+rm+1] - qz);
        if (m > 0.f && m*m > bound + SLOP) break;
      }
    }
    int zlo = max(cz-r, 0), zhi = min(cz+r, G-1);
    for (int z = zlo; z <= zhi; ++z) {
      bool zf = (z == cz-r) || (z == cz+r);
      int ylo = max(cy-r, 0), yhi = min(cy+r, G-1);
      for (int y = ylo; y <= yhi; ++y) {
        bool yf = (y == cy-r) || (y == cy+r);
        if (zf || yf) {
          prow(y, z, max(cx-r, 0), min(cx+r, G-1));
        } else {
          if (cx-r >= 0)   prow(y, z, cx-r, cx-r);
          if (cx+r <= G-1) prow(y, z, cx+r, cx+r);
        }
      }
    }
  }

  // merge the 4 per-lane sorted top-16 lists (bitonic, 2 rounds)
#pragma unroll
  for (int stage = 0; stage < 2; ++stage) {
    const int msk = 1 << stage;
    float bd[KK]; int bi[KK];
#pragma unroll
    for (int i = 0; i < KK; ++i) {
      bd[i] = __shfl_xor(dl[i], msk, 64);
      bi[i] = __shfl_xor(il[i], msk, 64);
    }
#pragma unroll
    for (int i = 0; i < KK; ++i) {        // keep 16 smallest of union (bitonic seq)
      bool take = bd[KK-1-i] < dl[i];
      dl[i] = take ? bd[KK-1-i] : dl[i];
      il[i] = take ? bi[KK-1-i] : il[i];
    }
#pragma unroll
    for (int d0 = 8; d0 > 0; d0 >>= 1) {  // bitonic sort-ascending network
#pragma unroll
      for (int i = 0; i < KK; ++i) {
        if ((i & d0) == 0) {
          int j = i + d0;
          bool sw = dl[j] < dl[i];
          float td = sw ? dl[j] : dl[i]; float tu = sw ? dl[i] : dl[j];
          dl[i] = td; dl[j] = tu;
          int ti = sw ? il[j] : il[i]; int tj = sw ? il[i] : il[j];
          il[i] = ti; il[j] = tj;
        }
      }
    }
  }

  int qn = sortid[t];
  size_t row = ((size_t)(b*NPTS + qn))*KK;
#pragma unroll
  for (int i = 0; i < KK; ++i) {
    if ((i >> 2) == sub) oidx[row + i] = sortid[il[i]];   // static reg index, no races
  }
}

// ---------------- mlp1 (leaky 0.2) + shortcut BN stats ----------------
__global__ void k_mlp1(const float* __restrict__ features,
                       const float* __restrict__ W1, const float* __restrict__ b1,
                       const float* __restrict__ Wsc, const float* __restrict__ bsc,
                       float* __restrict__ x1, float* __restrict__ stats) {
  __shared__ float sW1[128], sb1[16], sWsc[512], sbsc[64];
  int tid = threadIdx.x;
  if (tid < 128) sW1[tid] = W1[tid];
  if (tid < 16)  sb1[tid] = b1[tid];
  if (tid < 64)  sbsc[tid] = bsc[tid];
  for (int i = tid; i < 512; i += 256) sWsc[i] = Wsc[i];
  __syncthreads();
  int q = blockIdx.x*256 + tid;
  int b = q >> 15, n = q & (NPTS-1);
  float f[8];
#pragma unroll
  for (int c = 0; c < 8; ++c) f[c] = features[((size_t)b*8 + c)*NPTS + n];
#pragma unroll
  for (int co = 0; co < 16; ++co) {
    float a = sb1[co];
#pragma unroll
    for (int c = 0; c < 8; ++c) a += f[c]*sW1[co*8+c];
    x1[(size_t)q*16 + co] = a > 0.f ? a : 0.2f*a;
  }
  int lane = tid & 63;
#pragma unroll
  for (int co = 0; co < 64; ++co) {
    float a = sbsc[co];
#pragma unroll
    for (int c = 0; c < 8; ++c) a += f[c]*sWsc[co*8+c];
    float s = wred64(a), ss = wred64(a*a);
    if (lane == 0) { atomicAdd(&stats[S_SC+co], s); atomicAdd(&stats[S_SC+64+co], ss); }
  }
}

// ---------------- BN stats for BOTH LSE geometric encodings ----------------
__global__ void k_lsestats(const float* __restrict__ coords, const int* __restrict__ idx,
                           const float* __restrict__ Wl1, const float* __restrict__ bl1,
                           const float* __restrict__ Wl2, const float* __restrict__ bl2,
                           float* __restrict__ stats) {
  __shared__ float sW1[160], sb1[16], sW2[160], sb2[16];
  __shared__ float red[4][64];
  int tid = threadIdx.x;
  for (int i = tid; i < 160; i += 256) { sW1[i] = Wl1[i]; sW2[i] = Wl2[i]; }
  if (tid < 16) { sb1[tid] = bl1[tid]; sb2[tid] = bl2[tid]; }
  __syncthreads();
  int t = blockIdx.x*256 + tid;         // (b,n,k) flat
  int q = t >> 4;
  int b = q >> 15, n = q & (NPTS-1);
  const float* cb = coords + (size_t)b*(NPTS*3);
  int j = idx[t];
  float cx = cb[n*3], cy = cb[n*3+1], cz = cb[n*3+2];
  float px = cb[j*3], py = cb[j*3+1], pz = cb[j*3+2];
  float cat[10] = {cx,cy,cz,px,py,pz,cx-px,cy-py,cz-pz,1.f};
  int wave = tid >> 6, lane = tid & 63;
#pragma unroll
  for (int co = 0; co < 16; ++co) {
    float a1 = sb1[co], a2 = sb2[co];
#pragma unroll
    for (int d0 = 0; d0 < 10; ++d0) { a1 += cat[d0]*sW1[co*10+d0]; a2 += cat[d0]*sW2[co*10+d0]; }
    float s1 = wred64(a1), q1 = wred64(a1*a1);
    float s2 = wred64(a2), q2 = wred64(a2*a2);
    if (lane == 0) { red[wave][co]=s1; red[wave][16+co]=q1; red[wave][32+co]=s2; red[wave][48+co]=q2; }
  }
  __syncthreads();
  if (tid < 64) {
    float v = red[0][tid] + red[1][tid] + red[2][tid] + red[3][tid];
    int grp = tid >> 4, c = tid & 15;
    int off = (grp == 0) ? (S_L1 + c) : (grp == 1) ? (S_L1 + 16 + c)
            : (grp == 2) ? (S_L2 + c) : (S_L2 + 16 + c);
    atomicAdd(&stats[off], v);
  }
}

// ---------------- BN finalize ----------------
__global__ void k_bnfin(const float* __restrict__ stats, float* __restrict__ coef,
                        const float* __restrict__ gam, const float* __restrict__ bet,
                        int soff, int coff, int nch, float invc) {
  int c = threadIdx.x;
  if (c < nch) {
    float m = stats[soff + c]*invc;
    float v = stats[soff + nch + c]*invc - m*m;
    float a = gam[c]*rsqrtf(v + EPS);
    coef[coff + c] = a;
    coef[coff + nch + c] = bet[c] - m*a;
  }
}

// ---------------- LSE1 + attentive pooling 1 ----------------
__launch_bounds__(256)
__global__ void k_att1(const float* __restrict__ coords, const int* __restrict__ idx,
                       const float* __restrict__ x1ws,
                       const float* __restrict__ Wl1, const float* __restrict__ bl1,
                       const float* __restrict__ Ws1, const float* __restrict__ Wp1,
                       const float* __restrict__ bp1, const float* __restrict__ coef,
                       float* __restrict__ t2, float* __restrict__ stats) {
  __shared__ float sWl[160], sbl[16];
  __shared__ float sWs[1024];
  __shared__ float sWpT[512], sbp[16];
  __shared__ float lsum[16], lsq[16];
  int tid = threadIdx.x;
  for (int i = tid; i < 160; i += 256) { int c = i/10; sWl[i] = Wl1[i]*coef[C_L1 + c]; }
  if (tid < 16) sbl[tid] = bl1[tid]*coef[C_L1+tid] + coef[C_L1+16+tid];
  for (int i = tid; i < 1024; i += 256) sWs[i] = Ws1[i];
  for (int i = tid; i < 512; i += 256) { int co = i >> 4, cp = i & 15; sWpT[i] = Wp1[cp*32 + co]; }
  if (tid < 16) { sbp[tid] = bp1[tid]; lsum[tid] = 0.f; lsq[tid] = 0.f; }
  __syncthreads();
  int gp = blockIdx.x*16 + (tid >> 4);
  int k  = tid & 15;
  int b = gp >> 15, n = gp & (NPTS-1);
  const float* cb = coords + (size_t)b*(NPTS*3);
  int j = idx[(size_t)gp*KK + k];
  float cx = cb[n*3], cy = cb[n*3+1], cz = cb[n*3+2];
  float px = cb[j*3], py = cb[j*3+1], pz = cb[j*3+2];
  float cat[10] = {cx,cy,cz,px,py,pz,cx-px,cy-py,cz-pz,1.f};
  float x[32];
#pragma unroll
  for (int co = 0; co < 16; ++co) {
    float a = sbl[co];
#pragma unroll
    for (int d0 = 0; d0 < 10; ++d0) a += cat[d0]*sWl[co*10+d0];
    x[co] = a > 0.f ? a : 0.f;
  }
  {
    const float4* xp = (const float4*)(x1ws + (size_t)gp*16);
    float4 u0 = xp[0], u1 = xp[1], u2 = xp[2], u3 = xp[3];
    x[16]=u0.x; x[17]=u0.y; x[18]=u0.z; x[19]=u0.w;
    x[20]=u1.x; x[21]=u1.y; x[22]=u1.z; x[23]=u1.w;
    x[24]=u2.x; x[25]=u2.y; x[26]=u2.z; x[27]=u2.w;
    x[28]=u3.x; x[29]=u3.y; x[30]=u3.z; x[31]=u3.w;
  }
  float tacc = sbp[k];
#pragma unroll
  for (int co = 0; co < 32; ++co) {
    float s = 0.f;
#pragma unroll
    for (int ci = 0; ci < 32; ++ci) s += x[ci]*sWs[co*32+ci];
    float m = s;
#pragma unroll
    for (int msk = 8; msk > 0; msk >>= 1) m = fmaxf(m, __shfl_xor(m, msk, 16));
    float e = __expf(s - m);
    float se = e;
#pragma unroll
    for (int msk = 8; msk > 0; msk >>= 1) se += __shfl_xor(se, msk, 16);
    float w = e/se;
    float fv = w*x[co];
#pragma unroll
    for (int msk = 8; msk > 0; msk >>= 1) fv += __shfl_xor(fv, msk, 16);
    tacc += fv*sWpT[co*16+k];
  }
  t2[(size_t)gp*16 + k] = tacc;
  atomicAdd(&lsum[k], tacc);
  atomicAdd(&lsq[k], tacc*tacc);
  __syncthreads();
  if (tid < 16) { atomicAdd(&stats[S_P1+tid], lsum[tid]); atomicAdd(&stats[S_P1+16+tid], lsq[tid]); }
}

// ---------------- LSE2 + attentive pooling 2 ----------------
__launch_bounds__(256)
__global__ void k_att2(const float* __restrict__ coords, const int* __restrict__ idx,
                       const float* __restrict__ t2ws,
                       const float* __restrict__ Wl2, const float* __restrict__ bl2,
                       const float* __restrict__ Ws2, const float* __restrict__ Wp2,
                       const float* __restrict__ bp2, const float* __restrict__ coef,
                       float* __restrict__ t4, float* __restrict__ stats) {
  __shared__ float sWl[160], sbl[16];
  __shared__ float sWs[1024];
  __shared__ float sWpT[1024], sbp[32];
  __shared__ float sa1[16], sc1[16];
  __shared__ float lsum[32], lsq[32];
  int tid = threadIdx.x;
  for (int i = tid; i < 160; i += 256) { int c = i/10; sWl[i] = Wl2[i]*coef[C_L2 + c]; }
  if (tid < 16) sbl[tid] = bl2[tid]*coef[C_L2+tid] + coef[C_L2+16+tid];
  for (int i = tid; i < 1024; i += 256) {
    sWs[i] = Ws2[i];
    int co = i >> 5, cp = i & 31; sWpT[i] = Wp2[cp*32 + co];
  }
  if (tid < 32) { sbp[tid] = bp2[tid]; lsum[tid]=0.f; lsq[tid]=0.f; }
  if (tid < 16) { sa1[tid] = coef[C_P1+tid]; sc1[tid] = coef[C_P1+16+tid]; }
  __syncthreads();
  int gp = blockIdx.x*16 + (tid >> 4);
  int k  = tid & 15;
  int b = gp >> 15, n = gp & (NPTS-1);
  const float* cb = coords + (size_t)b*(NPTS*3);
  int j = idx[(size_t)gp*KK + k];
  float cx = cb[n*3], cy = cb[n*3+1], cz = cb[n*3+2];
  float px = cb[j*3], py = cb[j*3+1], pz = cb[j*3+2];
  float cat[10] = {cx,cy,cz,px,py,pz,cx-px,cy-py,cz-pz,1.f};
  float x[32];
#pragma unroll
  for (int co = 0; co < 16; ++co) {
    float a = sbl[co];
#pragma unroll
    for (int d0 = 0; d0 < 10; ++d0) a += cat[d0]*sWl[co*10+d0];
    x[co] = a > 0.f ? a : 0.f;
  }
  {
    const float4* xp = (const float4*)(t2ws + (size_t)gp*16);
    float4 u0 = xp[0], u1 = xp[1], u2 = xp[2], u3 = xp[3];
    float xv[16] = {u0.x,u0.y,u0.z,u0.w, u1.x,u1.y,u1.z,u1.w,
                    u2.x,u2.y,u2.z,u2.w, u3.x,u3.y,u3.z,u3.w};
#pragma unroll
    for (int c = 0; c < 16; ++c) {
      float v = xv[c]*sa1[c] + sc1[c];
      x[16+c] = v > 0.f ? v : 0.f;
    }
  }
  float tacc0 = sbp[k], tacc1 = sbp[k+16];
#pragma unroll
  for (int co = 0; co < 32; ++co) {
    float s = 0.f;
#pragma unroll
    for (int ci = 0; ci < 32; ++ci) s += x[ci]*sWs[co*32+ci];
    float m = s;
#pragma unroll
    for (int msk = 8; msk > 0; msk >>= 1) m = fmaxf(m, __shfl_xor(m, msk, 16));
    float e = __expf(s - m);
    float se = e;
#pragma unroll
    for (int msk = 8; msk > 0; msk >>= 1) se += __shfl_xor(se, msk, 16);
    float w = e/se;
    float fv = w*x[co];
#pragma unroll
    for (int msk = 8; msk > 0; msk >>= 1) fv += __shfl_xor(fv, msk, 16);
    tacc0 += fv*sWpT[co*32+k];
    tacc1 += fv*sWpT[co*32+k+16];
  }
  t4[(size_t)gp*32 + k]      = tacc0;
  t4[(size_t)gp*32 + k + 16] = tacc1;
  atomicAdd(&lsum[k], tacc0);      atomicAdd(&lsq[k], tacc0*tacc0);
  atomicAdd(&lsum[k+16], tacc1);   atomicAdd(&lsq[k+16], tacc1*tacc1);
  __syncthreads();
  if (tid < 32) { atomicAdd(&stats[S_P2+tid], lsum[tid]); atomicAdd(&stats[S_P2+32+tid], lsq[tid]); }
}

// ---------------- final: mlp2 + BN'd shortcut + leaky 0.01 ----------------
__global__ void k_final(const float* __restrict__ t4ws, const float* __restrict__ features,
                        const float* __restrict__ W2, const float* __restrict__ b2,
                        const float* __restrict__ Wsc, const float* __restrict__ bsc,
                        const float* __restrict__ coef, float* __restrict__ out) {
  __shared__ float sW2[2048], sb2[64], sWscF[512], sbscF[64], sa[32], scc[32];
  int tid = threadIdx.x;
  for (int i = tid; i < 2048; i += 256) sW2[i] = W2[i];
  if (tid < 64) sb2[tid] = b2[tid];
  for (int i = tid; i < 512; i += 256) { int c2 = i >> 3; sWscF[i] = Wsc[i]*coef[C_SC + c2]; }
  if (tid < 64) sbscF[tid] = bsc[tid]*coef[C_SC+tid] + coef[C_SC+64+tid];
  if (tid < 32) { sa[tid] = coef[C_P2+tid]; scc[tid] = coef[C_P2+32+tid]; }
  __syncthreads();
  int q = blockIdx.x*256 + tid;
  int b = q >> 15, n = q & (NPTS-1);
  float x3[32];
  const float4* tp = (const float4*)(t4ws + (size_t)q*32);
#pragma unroll
  for (int i = 0; i < 8; ++i) {
    float4 u = tp[i];
    float v0 = u.x*sa[4*i+0] + scc[4*i+0];
    float v1 = u.y*sa[4*i+1] + scc[4*i+1];
    float v2 = u.z*sa[4*i+2] + scc[4*i+2];
    float v3 = u.w*sa[4*i+3] + scc[4*i+3];
    x3[4*i+0] = v0 > 0.f ? v0 : 0.f;
    x3[4*i+1] = v1 > 0.f ? v1 : 0.f;
    x3[4*i+2] = v2 > 0.f ? v2 : 0.f;
    x3[4*i+3] = v3 > 0.f ? v3 : 0.f;
  }
  float f[8];
#pragma unroll
  for (int c = 0; c < 8; ++c) f[c] = features[((size_t)b*8+c)*NPTS + n];
  for (int c2 = 0; c2 < 64; ++c2) {
    float acc = sb2[c2];
#pragma unroll
    for (int co = 0; co < 32; ++co) acc += x3[co]*sW2[c2*32+co];
    float sv = sbscF[c2];
#pragma unroll
    for (int c = 0; c < 8; ++c) sv += f[c]*sWscF[c2*8+c];
    float o = acc + sv;
    out[((size_t)b*64 + c2)*NPTS + n] = o > 0.f ? o : 0.01f*o;
  }
}

extern "C" void kernel_launch(void* const* d_in, const int* in_sizes, int n_in,
                              void* d_out, int out_size, void* d_ws, size_t ws_size,
                              hipStream_t stream) {
  const float* coords   = (const float*)d_in[0];
  const float* features = (const float*)d_in[1];
  const float* W1  = (const float*)d_in[2];
  const float* b1  = (const float*)d_in[3];
  const float* Wl1 = (const float*)d_in[4];
  const float* bl1 = (const float*)d_in[5];
  const float* gl1 = (const float*)d_in[6];
  const float* bl1b= (const float*)d_in[7];
  const float* Ws1 = (const float*)d_in[8];
  const float* Wp1 = (const float*)d_in[9];
  const float* bp1 = (const float*)d_in[10];
  const float* gp1 = (const float*)d_in[11];
  const float* bp1b= (const float*)d_in[12];
  const float* Wl2 = (const float*)d_in[13];
  const float* bl2 = (const float*)d_in[14];
  const float* gl2 = (const float*)d_in[15];
  const float* bl2b= (const float*)d_in[16];
  const float* Ws2 = (const float*)d_in[17];
  const float* Wp2 = (const float*)d_in[18];
  const float* bp2 = (const float*)d_in[19];
  const float* gp2 = (const float*)d_in[20];
  const float* bp2b= (const float*)d_in[21];
  const float* W2  = (const float*)d_in[22];
  const float* b2  = (const float*)d_in[23];
  const float* Wsc = (const float*)d_in[24];
  const float* bsc = (const float*)d_in[25];
  const float* gsc = (const float*)d_in[26];
  const float* bscb= (const float*)d_in[27];

  float* wsF  = (float*)d_ws;
  int*   wsI  = (int*)d_ws;
  int*   idxp = wsI;
  float* x1p  = wsF + WS_X1;
  float* t2p  = wsF + WS_T2;
  float* t4p  = wsF + WS_T4;
  float* stat = wsF + WS_STAT;
  float* coef = wsF + WS_COEF;
  int*   gcnt = wsI + WS_GCNT;
  int*   gsta = wsI + WS_GSTART;
  int*   gcel = wsI + WS_CELLID;
  int*   sid  = wsI + WS_SORTID;
  float4* csrt = (float4*)(wsF + WS_CSORT);
  unsigned int* bbox = (unsigned int*)(wsI + WS_BBOX);
  int*   hist = wsI + WS_HIST;
  int*   strt = wsI + WS_STARTS;          // aliases hist (dead after k_edges)
  float* edge = wsF + WS_EDGE;
  float* outp = (float*)d_out;

  hipLaunchKernelGGL(k_zero_all, dim3(48), dim3(256), 0, stream, stat, gcnt, hist, bbox);
  hipLaunchKernelGGL(k_bbox,    dim3(NQ/256), dim3(256), 0, stream, coords, bbox);
  hipLaunchKernelGGL(k_hist,    dim3(NQ/256), dim3(256), 0, stream, coords, bbox, hist);
  hipLaunchKernelGGL(k_edges,   dim3(6), dim3(256), 0, stream, hist, bbox, edge);
  hipLaunchKernelGGL(k_bin,     dim3(NQ/256), dim3(256), 0, stream, coords, edge, gcel, gcnt);
  hipLaunchKernelGGL(k_alloc,   dim3(1), dim3(1024), 0, stream, gcnt, gsta, strt);
  hipLaunchKernelGGL(k_scatter, dim3(NQ/256), dim3(256), 0, stream, coords, gcel, gsta, csrt, sid);
  hipLaunchKernelGGL(k_knn_grid,dim3(NQ/64), dim3(256), 0, stream,
                     csrt, sid, strt, edge, idxp);
  hipLaunchKernelGGL(k_mlp1, dim3(NQ/256), dim3(256), 0, stream,
                     features, W1, b1, Wsc, bsc, x1p, stat);
  hipLaunchKernelGGL(k_lsestats, dim3((NQ*KK)/256), dim3(256), 0, stream,
                     coords, idxp, Wl1, bl1, Wl2, bl2, stat);
  hipLaunchKernelGGL(k_bnfin, dim3(1), dim3(64), 0, stream, stat, coef, gl1, bl1b,
                     S_L1, C_L1, 16, 1.f/(float)((size_t)NQ*KK));
  hipLaunchKernelGGL(k_bnfin, dim3(1), dim3(64), 0, stream, stat, coef, gl2, bl2b,
                     S_L2, C_L2, 16, 1.f/(float)((size_t)NQ*KK));
  hipLaunchKernelGGL(k_bnfin, dim3(1), dim3(64), 0, stream, stat, coef, gsc, bscb,
                     S_SC, C_SC, 64, 1.f/(float)NQ);
  hipLaunchKernelGGL(k_att1, dim3(NQ/16), dim3(256), 0, stream,
                     coords, idxp, x1p, Wl1, bl1, Ws1, Wp1, bp1, coef, t2p, stat);
  hipLaunchKernelGGL(k_bnfin, dim3(1), dim3(64), 0, stream, stat, coef, gp1, bp1b,
                     S_P1, C_P1, 16, 1.f/(float)NQ);
  hipLaunchKernelGGL(k_att2, dim3(NQ/16), dim3(256), 0, stream,
                     coords, idxp, t2p, Wl2, bl2, Ws2, Wp2, bp2, coef, t4p, stat);
  hipLaunchKernelGGL(k_bnfin, dim3(1), dim3(64), 0, stream, stat, coef, gp2, bp2b,
                     S_P2, C_P2, 32, 1.f/(float)NQ);
  hipLaunchKernelGGL(k_final, dim3(NQ/256), dim3(256), 0, stream,
                     t4p, features, W2, b2, Wsc, bsc, coef, outp);
}

// Round 5
// 1924.274 us; speedup vs baseline: 2.4889x; 1.1325x over previous
//
#include <hip/hip_runtime.h>
#include <math.h>

#define NPTS  32768
#define NB    2
#define NQ    (NB*NPTS)
#define KK    16
#define EPS   1e-6f
#define G     16
#define G3    (G*G*G)
#define HB    2048
#define SLOP  0.05f
#define LPQ   16

// stats / coef element offsets
#define S_L1 0
#define S_L2 32
#define S_P1 64
#define S_P2 96
#define S_SC 160
#define C_L1 0
#define C_L2 32
#define C_P1 64
#define C_P2 96
#define C_SC 160

// workspace element offsets (4-byte units)
#define WS_X1     (NQ*16)
#define WS_T2     (NQ*32)
#define WS_T4     (NQ*48)
#define WS_STAT   (NQ*80)
#define WS_COEF   (WS_STAT + 512)
#define WS_GCNT   (WS_STAT + 1024)
#define WS_GSTART (WS_GCNT + 2*G3)
#define WS_CELLID (WS_GSTART + 2*G3)
#define WS_SORTID (WS_CELLID + NQ)
#define WS_CSORT  (WS_SORTID + NQ)      /* float4 x NQ (16B-aligned) */
#define WS_BBOX   (WS_CSORT + 4*NQ)
#define WS_HIST   (WS_BBOX + 16)
#define WS_EDGE   (WS_HIST + 6*HB)
#define WS_STARTS WS_HIST               /* starts aliases hist (dead after k_edges) */

__device__ __forceinline__ float wred64(float v) {
#pragma unroll
  for (int m = 32; m > 0; m >>= 1) v += __shfl_xor(v, m, 64);
  return v;
}

// order-preserving float <-> uint encoding for atomic min/max
__device__ __forceinline__ unsigned int encf(float f) {
  unsigned int u = __float_as_uint(f);
  return (u & 0x80000000u) ? ~u : (u | 0x80000000u);
}
__device__ __forceinline__ float decf(unsigned int u) {
  return (u & 0x80000000u) ? __uint_as_float(u & 0x7fffffffu) : __uint_as_float(~u);
}

// 4-step binary search over G=16 quantile edges; e[0] <= x guaranteed
__device__ __forceinline__ int bs16(const float* e, float x) {
  int c = (x >= e[8]) ? 8 : 0;
  c += (x >= e[c+4]) ? 4 : 0;
  c += (x >= e[c+2]) ? 2 : 0;
  c += (x >= e[c+1]) ? 1 : 0;
  return c;
}

// ---------------- zero stats + counters + hist + bbox ----------------
__global__ void k_zero_all(float* __restrict__ stats, int* __restrict__ gcnt,
                           int* __restrict__ hist, unsigned int* __restrict__ bbox) {
  int i = blockIdx.x*256 + threadIdx.x;       // grid covers 12288
  if (i < 2*G3) gcnt[i] = 0;
  if (i < 6*HB) hist[i] = 0;
  if (i < 320)  stats[i] = 0.f;
  if (i < 12)   bbox[i] = ((i % 6) < 3) ? 0xFFFFFFFFu : 0u;
}

// ---------------- per-batch exact bounding box ----------------
__global__ void k_bbox(const float* __restrict__ coords, unsigned int* __restrict__ bbox) {
  __shared__ unsigned int rmn[3][4], rmx[3][4];
  int tid = threadIdx.x;
  int t = blockIdx.x*256 + tid;
  int b = t >> 15, n = t & (NPTS-1);
  const float* cb = coords + (size_t)b*(NPTS*3);
  unsigned int e[3] = { encf(cb[n*3+0]), encf(cb[n*3+1]), encf(cb[n*3+2]) };
  unsigned int mn[3] = { e[0], e[1], e[2] }, mx[3] = { e[0], e[1], e[2] };
#pragma unroll
  for (int s = 32; s > 0; s >>= 1) {
#pragma unroll
    for (int a = 0; a < 3; ++a) {
      unsigned int o1 = (unsigned int)__shfl_xor((int)mn[a], s, 64);
      unsigned int o2 = (unsigned int)__shfl_xor((int)mx[a], s, 64);
      mn[a] = mn[a] < o1 ? mn[a] : o1;
      mx[a] = mx[a] > o2 ? mx[a] : o2;
    }
  }
  int wave = tid >> 6, lane = tid & 63;
  if (lane == 0) {
#pragma unroll
    for (int a = 0; a < 3; ++a) { rmn[a][wave] = mn[a]; rmx[a][wave] = mx[a]; }
  }
  __syncthreads();
  if (tid < 3) {
    unsigned int a0 = min(min(rmn[tid][0], rmn[tid][1]), min(rmn[tid][2], rmn[tid][3]));
    unsigned int A0 = max(max(rmx[tid][0], rmx[tid][1]), max(rmx[tid][2], rmx[tid][3]));
    atomicMin(&bbox[b*6 + tid], a0);
    atomicMax(&bbox[b*6 + 3 + tid], A0);
  }
}

// ---------------- per-axis fine histogram ----------------
__global__ void k_hist(const float* __restrict__ coords, const unsigned int* __restrict__ bbox,
                       int* __restrict__ hist) {
  int t = blockIdx.x*256 + threadIdx.x;
  int b = t >> 15, n = t & (NPTS-1);
  const float* cb = coords + (size_t)b*(NPTS*3);
#pragma unroll
  for (int a = 0; a < 3; ++a) {
    float l = decf(bbox[b*6+a]), h = decf(bbox[b*6+3+a]);
    float ex = (h - l)*(1.f + 4e-7f) + 1e-30f;
    float inv = (float)HB/ex;
    int bin = (int)((cb[n*3+a] - l)*inv);
    bin = min(HB-1, max(0, bin));
    atomicAdd(&hist[(b*3+a)*HB + bin], 1);
  }
}

// ---------------- equal-frequency edges from histogram cdf ----------------
__global__ void k_edges(const int* __restrict__ hist, const unsigned int* __restrict__ bbox,
                        float* __restrict__ edges) {
  __shared__ int part[256];
  int p = blockIdx.x;                 // pair = b*3 + a, 6 blocks
  int b = p/3, a = p - b*3;
  int tid = threadIdx.x;
  const int* h = hist + p*HB;
  int v[8]; int s = 0;
#pragma unroll
  for (int i = 0; i < 8; ++i) { v[i] = h[tid*8 + i]; s += v[i]; }
  part[tid] = s;
  __syncthreads();
  for (int off = 1; off < 256; off <<= 1) {
    int x = part[tid];
    int y = (tid >= off) ? part[tid-off] : 0;
    __syncthreads();
    part[tid] = x + y;
    __syncthreads();
  }
  float l = decf(bbox[b*6+a]), hi = decf(bbox[b*6+3+a]);
  float ex = (hi - l)*(1.f + 4e-7f) + 1e-30f;
  float bw = ex*(1.f/(float)HB);
  int c = part[tid] - s;              // exclusive base
#pragma unroll
  for (int i = 0; i < 8; ++i) {
    int lo_c = c; c += v[i];
#pragma unroll
    for (int g = 1; g < G; ++g) {
      int tq = g*(NPTS/G);
      if (lo_c < tq && c >= tq) edges[p*(G+1) + g] = l + bw*(float)(tid*8 + i + 1);
    }
  }
  if (tid == 0) { edges[p*(G+1)] = l; edges[p*(G+1) + G] = hi + fabsf(hi)*1e-6f + 1e-20f; }
}

// ---------------- bin points into quantile cells ----------------
__global__ void k_bin(const float* __restrict__ coords, const float* __restrict__ edges,
                      int* __restrict__ cellid, int* __restrict__ gcnt) {
  __shared__ float se[3][G+1];
  int tid = threadIdx.x;
  int t = blockIdx.x*256 + tid;
  int b = t >> 15, n = t & (NPTS-1);
  if (tid < 3*(G+1)) se[tid/(G+1)][tid%(G+1)] = edges[b*3*(G+1) + tid];
  __syncthreads();
  const float* cb = coords + (size_t)b*(NPTS*3);
  int c0 = bs16(se[0], cb[n*3+0]);
  int c1 = bs16(se[1], cb[n*3+1]);
  int c2 = bs16(se[2], cb[n*3+2]);
  int cid = b*G3 + (c2*G + c1)*G + c0;
  cellid[t] = cid;
  atomicAdd(&gcnt[cid], 1);
}

// ---------------- deterministic global scan over all 8192 cells ----------------
// writes gstart (mutated by scatter) AND starts (+sentinel, read by knn)
__global__ void k_alloc(const int* __restrict__ gcnt, int* __restrict__ gstart,
                        int* __restrict__ starts) {
  __shared__ int part[1024];
  int tid = threadIdx.x;
  int v[8]; int s = 0;
#pragma unroll
  for (int i = 0; i < 8; ++i) { v[i] = gcnt[tid*8 + i]; s += v[i]; }
  part[tid] = s;
  __syncthreads();
  for (int off = 1; off < 1024; off <<= 1) {
    int x = part[tid];
    int y = (tid >= off) ? part[tid-off] : 0;
    __syncthreads();
    part[tid] = x + y;
    __syncthreads();
  }
  int base = part[tid] - s;
#pragma unroll
  for (int i = 0; i < 8; ++i) { gstart[tid*8 + i] = base; starts[tid*8 + i] = base; base += v[i]; }
  if (tid == 1023) starts[2*G3] = NQ;
}

// ---------------- scatter: packed float4 + original id, cell-sorted ----------------
__global__ void k_scatter(const float* __restrict__ coords, const int* __restrict__ cellid,
                          int* __restrict__ gstart, float4* __restrict__ csort,
                          int* __restrict__ sortid) {
  int t = blockIdx.x*256 + threadIdx.x;
  int b = t >> 15, n = t & (NPTS-1);
  const float* cb = coords + (size_t)b*(NPTS*3);
  int cid = cellid[t];
  int pos = atomicAdd(&gstart[cid], 1);
  float x = cb[n*3+0], y = cb[n*3+1], z = cb[n*3+2];
  csort[pos] = make_float4(x, y, z, x*x + y*y + z*z);
  sortid[pos] = n;
}

// ---------------- exact KNN: 16 lanes/query, LDS starts table ----------------
__launch_bounds__(256)
__global__ void k_knn_grid(const float4* __restrict__ csort, const int* __restrict__ sortid,
                           const int* __restrict__ starts, const float* __restrict__ edges,
                           int* __restrict__ oidx) {
  __shared__ int   ls[G3+1];                // whole per-batch cell-range table (16.4 KB)
  __shared__ float se[3][G+1];
  int tid = threadIdx.x;
  int t = blockIdx.x*16 + (tid >> 4);       // query = global sorted position
  int sub = tid & 15;                       // lane within 16-lane group
  int b = t >> 15;                          // 16 | 32768 -> uniform per block
  if (tid < 3*(G+1)) se[tid/(G+1)][tid%(G+1)] = edges[b*3*(G+1) + tid];
  for (int i = tid; i <= G3; i += 256) ls[i] = starts[b*G3 + i];
  __syncthreads();
  float4 qv = csort[t];
  const float qx = qv.x, qy = qv.y, qz = qv.z, qsq = qv.w;
  const int cx = bs16(se[0], qx), cy = bs16(se[1], qy), cz = bs16(se[2], qz);

  float dl[KK]; int il[KK];
#pragma unroll
  for (int i = 0; i < KK; ++i) { dl[i] = 1e30f; il[i] = 0; }

  auto prange = [&](int s0, int e0) {
    for (int i = s0 + sub; i < e0; i += LPQ) {
      float4 p = csort[i];
      float d = qsq + p.w - 2.f*(qx*p.x + qy*p.y + qz*p.z);   // == reference formula
      if (d < dl[KK-1]) {                                      // strict <
        float cd = d; int ci = i;
#pragma unroll
        for (int i2 = 0; i2 < KK; ++i2) {
          bool sw = cd < dl[i2];
          float td = dl[i2]; int ti = il[i2];
          dl[i2] = sw ? cd : td; il[i2] = sw ? ci : ti;
          cd = sw ? td : cd;    ci = sw ? ti : ci;
        }
      }
    }
  };
  auto prow = [&](int y, int z, int xa, int xb) {
    int c0 = (z*G + y)*G + xa;
    prange(ls[c0], ls[c0 + (xb - xa) + 1]);
  };

  for (int r = 0; r <= G; ++r) {
    if (r >= 1) {
      int rm = r - 1;
      if (cx-rm <= 0 && cx+rm >= G-1 && cy-rm <= 0 && cy+rm >= G-1 &&
          cz-rm <= 0 && cz+rm >= G-1) break;                   // searched everything
      // group bound on true d16: 16 lane-minima are 16 distinct candidates
      float b0 = dl[0], b15 = dl[KK-1];
#pragma unroll
      for (int m = 1; m < 16; m <<= 1) {
        b0  = fmaxf(b0,  __shfl_xor(b0,  m, 16));
        b15 = fminf(b15, __shfl_xor(b15, m, 16));
      }
      float bound = fminf(b0, b15);
      if (bound < 1e29f) {
        float m = 1e30f;
        if (cx-rm > 0)   m = fminf(m, qx - se[0][cx-rm]);
        if (cx+rm < G-1) m = fminf(m, se[0][cx+rm+1] - qx);
        if (cy-rm > 0)   m = fminf(m, qy - se[1][cy-rm]);
        if (cy+rm < G-1) m = fminf(m, se[1][cy+rm+1] - qy);
        if (cz-rm > 0)   m = fminf(m, qz - se[2][cz-rm]);
        if (cz+rm < G-1) m = fminf(m, se[2][cz+rm+1] - qz);
        if (m > 0.f && m*m > bound + SLOP) break;
      }
    }
    int zlo = max(cz-r, 0), zhi = min(cz+r, G-1);
    for (int z = zlo; z <= zhi; ++z) {
      bool zf = (z == cz-r) || (z == cz+r);
      int ylo = max(cy-r, 0), yhi = min(cy+r, G-1);
      for (int y = ylo; y <= yhi; ++y) {
        bool yf = (y == cy-r) || (y == cy+r);
        if (zf || yf) {
          prow(y, z, max(cx-r, 0), min(cx+r, G-1));
        } else {
          if (cx-r >= 0)   prow(y, z, cx-r, cx-r);
          if (cx+r <= G-1) prow(y, z, cx+r, cx+r);
        }
      }
    }
  }

  // merge the 16 per-lane sorted top-16 lists (bitonic, 4 rounds)
#pragma unroll
  for (int stage = 0; stage < 4; ++stage) {
    const int msk = 1 << stage;
    float bd[KK]; int bi[KK];
#pragma unroll
    for (int i = 0; i < KK; ++i) {
      bd[i] = __shfl_xor(dl[i], msk, 16);
      bi[i] = __shfl_xor(il[i], msk, 16);
    }
#pragma unroll
    for (int i = 0; i < KK; ++i) {        // keep 16 smallest of union (bitonic seq)
      bool take = bd[KK-1-i] < dl[i];
      dl[i] = take ? bd[KK-1-i] : dl[i];
      il[i] = take ? bi[KK-1-i] : il[i];
    }
#pragma unroll
    for (int d0 = 8; d0 > 0; d0 >>= 1) {  // bitonic sort-ascending network
#pragma unroll
      for (int i = 0; i < KK; ++i) {
        if ((i & d0) == 0) {
          int j = i + d0;
          bool sw = dl[j] < dl[i];
          float td = sw ? dl[j] : dl[i]; float tu = sw ? dl[i] : dl[j];
          dl[i] = td; dl[j] = tu;
          int ti = sw ? il[j] : il[i]; int tj = sw ? il[i] : il[j];
          il[i] = ti; il[j] = tj;
        }
      }
    }
  }

  int qn = sortid[t];
  size_t row = ((size_t)(b*NPTS + qn))*KK;
#pragma unroll
  for (int i = 0; i < KK; ++i) {
    if (i == sub) oidx[row + i] = sortid[il[i]];   // static reg index, 1 store/lane
  }
}

// ---------------- mlp1 (leaky 0.2) + shortcut BN stats ----------------
__global__ void k_mlp1(const float* __restrict__ features,
                       const float* __restrict__ W1, const float* __restrict__ b1,
                       const float* __restrict__ Wsc, const float* __restrict__ bsc,
                       float* __restrict__ x1, float* __restrict__ stats) {
  __shared__ float sW1[128], sb1[16], sWsc[512], sbsc[64];
  int tid = threadIdx.x;
  if (tid < 128) sW1[tid] = W1[tid];
  if (tid < 16)  sb1[tid] = b1[tid];
  if (tid < 64)  sbsc[tid] = bsc[tid];
  for (int i = tid; i < 512; i += 256) sWsc[i] = Wsc[i];
  __syncthreads();
  int q = blockIdx.x*256 + tid;
  int b = q >> 15, n = q & (NPTS-1);
  float f[8];
#pragma unroll
  for (int c = 0; c < 8; ++c) f[c] = features[((size_t)b*8 + c)*NPTS + n];
#pragma unroll
  for (int co = 0; co < 16; ++co) {
    float a = sb1[co];
#pragma unroll
    for (int c = 0; c < 8; ++c) a += f[c]*sW1[co*8+c];
    x1[(size_t)q*16 + co] = a > 0.f ? a : 0.2f*a;
  }
  int lane = tid & 63;
#pragma unroll
  for (int co = 0; co < 64; ++co) {
    float a = sbsc[co];
#pragma unroll
    for (int c = 0; c < 8; ++c) a += f[c]*sWsc[co*8+c];
    float s = wred64(a), ss = wred64(a*a);
    if (lane == 0) { atomicAdd(&stats[S_SC+co], s); atomicAdd(&stats[S_SC+64+co], ss); }
  }
}

// ---------------- BN stats for BOTH LSE geometric encodings ----------------
__global__ void k_lsestats(const float* __restrict__ coords, const int* __restrict__ idx,
                           const float* __restrict__ Wl1, const float* __restrict__ bl1,
                           const float* __restrict__ Wl2, const float* __restrict__ bl2,
                           float* __restrict__ stats) {
  __shared__ float sW1[160], sb1[16], sW2[160], sb2[16];
  __shared__ float red[4][64];
  int tid = threadIdx.x;
  for (int i = tid; i < 160; i += 256) { sW1[i] = Wl1[i]; sW2[i] = Wl2[i]; }
  if (tid < 16) { sb1[tid] = bl1[tid]; sb2[tid] = bl2[tid]; }
  __syncthreads();
  int t = blockIdx.x*256 + tid;         // (b,n,k) flat
  int q = t >> 4;
  int b = q >> 15, n = q & (NPTS-1);
  const float* cb = coords + (size_t)b*(NPTS*3);
  int j = idx[t];
  float cx = cb[n*3], cy = cb[n*3+1], cz = cb[n*3+2];
  float px = cb[j*3], py = cb[j*3+1], pz = cb[j*3+2];
  float cat[10] = {cx,cy,cz,px,py,pz,cx-px,cy-py,cz-pz,1.f};
  int wave = tid >> 6, lane = tid & 63;
#pragma unroll
  for (int co = 0; co < 16; ++co) {
    float a1 = sb1[co], a2 = sb2[co];
#pragma unroll
    for (int d0 = 0; d0 < 10; ++d0) { a1 += cat[d0]*sW1[co*10+d0]; a2 += cat[d0]*sW2[co*10+d0]; }
    float s1 = wred64(a1), q1 = wred64(a1*a1);
    float s2 = wred64(a2), q2 = wred64(a2*a2);
    if (lane == 0) { red[wave][co]=s1; red[wave][16+co]=q1; red[wave][32+co]=s2; red[wave][48+co]=q2; }
  }
  __syncthreads();
  if (tid < 64) {
    float v = red[0][tid] + red[1][tid] + red[2][tid] + red[3][tid];
    int grp = tid >> 4, c = tid & 15;
    int off = (grp == 0) ? (S_L1 + c) : (grp == 1) ? (S_L1 + 16 + c)
            : (grp == 2) ? (S_L2 + c) : (S_L2 + 16 + c);
    atomicAdd(&stats[off], v);
  }
}

// ---------------- BN finalize ----------------
__global__ void k_bnfin(const float* __restrict__ stats, float* __restrict__ coef,
                        const float* __restrict__ gam, const float* __restrict__ bet,
                        int soff, int coff, int nch, float invc) {
  int c = threadIdx.x;
  if (c < nch) {
    float m = stats[soff + c]*invc;
    float v = stats[soff + nch + c]*invc - m*m;
    float a = gam[c]*rsqrtf(v + EPS);
    coef[coff + c] = a;
    coef[coff + nch + c] = bet[c] - m*a;
  }
}

// ---------------- LSE1 + attentive pooling 1 ----------------
__launch_bounds__(256)
__global__ void k_att1(const float* __restrict__ coords, const int* __restrict__ idx,
                       const float* __restrict__ x1ws,
                       const float* __restrict__ Wl1, const float* __restrict__ bl1,
                       const float* __restrict__ Ws1, const float* __restrict__ Wp1,
                       const float* __restrict__ bp1, const float* __restrict__ coef,
                       float* __restrict__ t2, float* __restrict__ stats) {
  __shared__ float sWl[160], sbl[16];
  __shared__ float sWs[1024];
  __shared__ float sWpT[512], sbp[16];
  __shared__ float lsum[16], lsq[16];
  int tid = threadIdx.x;
  for (int i = tid; i < 160; i += 256) { int c = i/10; sWl[i] = Wl1[i]*coef[C_L1 + c]; }
  if (tid < 16) sbl[tid] = bl1[tid]*coef[C_L1+tid] + coef[C_L1+16+tid];
  for (int i = tid; i < 1024; i += 256) sWs[i] = Ws1[i];
  for (int i = tid; i < 512; i += 256) { int co = i >> 4, cp = i & 15; sWpT[i] = Wp1[cp*32 + co]; }
  if (tid < 16) { sbp[tid] = bp1[tid]; lsum[tid] = 0.f; lsq[tid] = 0.f; }
  __syncthreads();
  int gp = blockIdx.x*16 + (tid >> 4);
  int k  = tid & 15;
  int b = gp >> 15, n = gp & (NPTS-1);
  const float* cb = coords + (size_t)b*(NPTS*3);
  int j = idx[(size_t)gp*KK + k];
  float cx = cb[n*3], cy = cb[n*3+1], cz = cb[n*3+2];
  float px = cb[j*3], py = cb[j*3+1], pz = cb[j*3+2];
  float cat[10] = {cx,cy,cz,px,py,pz,cx-px,cy-py,cz-pz,1.f};
  float x[32];
#pragma unroll
  for (int co = 0; co < 16; ++co) {
    float a = sbl[co];
#pragma unroll
    for (int d0 = 0; d0 < 10; ++d0) a += cat[d0]*sWl[co*10+d0];
    x[co] = a > 0.f ? a : 0.f;
  }
  {
    const float4* xp = (const float4*)(x1ws + (size_t)gp*16);
    float4 u0 = xp[0], u1 = xp[1], u2 = xp[2], u3 = xp[3];
    x[16]=u0.x; x[17]=u0.y; x[18]=u0.z; x[19]=u0.w;
    x[20]=u1.x; x[21]=u1.y; x[22]=u1.z; x[23]=u1.w;
    x[24]=u2.x; x[25]=u2.y; x[26]=u2.z; x[27]=u2.w;
    x[28]=u3.x; x[29]=u3.y; x[30]=u3.z; x[31]=u3.w;
  }
  float tacc = sbp[k];
#pragma unroll
  for (int co = 0; co < 32; ++co) {
    float s = 0.f;
#pragma unroll
    for (int ci = 0; ci < 32; ++ci) s += x[ci]*sWs[co*32+ci];
    float m = s;
#pragma unroll
    for (int msk = 8; msk > 0; msk >>= 1) m = fmaxf(m, __shfl_xor(m, msk, 16));
    float e = __expf(s - m);
    float se = e;
#pragma unroll
    for (int msk = 8; msk > 0; msk >>= 1) se += __shfl_xor(se, msk, 16);
    float w = e/se;
    float fv = w*x[co];
#pragma unroll
    for (int msk = 8; msk > 0; msk >>= 1) fv += __shfl_xor(fv, msk, 16);
    tacc += fv*sWpT[co*16+k];
  }
  t2[(size_t)gp*16 + k] = tacc;
  atomicAdd(&lsum[k], tacc);
  atomicAdd(&lsq[k], tacc*tacc);
  __syncthreads();
  if (tid < 16) { atomicAdd(&stats[S_P1+tid], lsum[tid]); atomicAdd(&stats[S_P1+16+tid], lsq[tid]); }
}

// ---------------- LSE2 + attentive pooling 2 ----------------
__launch_bounds__(256)
__global__ void k_att2(const float* __restrict__ coords, const int* __restrict__ idx,
                       const float* __restrict__ t2ws,
                       const float* __restrict__ Wl2, const float* __restrict__ bl2,
                       const float* __restrict__ Ws2, const float* __restrict__ Wp2,
                       const float* __restrict__ bp2, const float* __restrict__ coef,
                       float* __restrict__ t4, float* __restrict__ stats) {
  __shared__ float sWl[160], sbl[16];
  __shared__ float sWs[1024];
  __shared__ float sWpT[1024], sbp[32];
  __shared__ float sa1[16], sc1[16];
  __shared__ float lsum[32], lsq[32];
  int tid = threadIdx.x;
  for (int i = tid; i < 160; i += 256) { int c = i/10; sWl[i] = Wl2[i]*coef[C_L2 + c]; }
  if (tid < 16) sbl[tid] = bl2[tid]*coef[C_L2+tid] + coef[C_L2+16+tid];
  for (int i = tid; i < 1024; i += 256) {
    sWs[i] = Ws2[i];
    int co = i >> 5, cp = i & 31; sWpT[i] = Wp2[cp*32 + co];
  }
  if (tid < 32) { sbp[tid] = bp2[tid]; lsum[tid]=0.f; lsq[tid]=0.f; }
  if (tid < 16) { sa1[tid] = coef[C_P1+tid]; sc1[tid] = coef[C_P1+16+tid]; }
  __syncthreads();
  int gp = blockIdx.x*16 + (tid >> 4);
  int k  = tid & 15;
  int b = gp >> 15, n = gp & (NPTS-1);
  const float* cb = coords + (size_t)b*(NPTS*3);
  int j = idx[(size_t)gp*KK + k];
  float cx = cb[n*3], cy = cb[n*3+1], cz = cb[n*3+2];
  float px = cb[j*3], py = cb[j*3+1], pz = cb[j*3+2];
  float cat[10] = {cx,cy,cz,px,py,pz,cx-px,cy-py,cz-pz,1.f};
  float x[32];
#pragma unroll
  for (int co = 0; co < 16; ++co) {
    float a = sbl[co];
#pragma unroll
    for (int d0 = 0; d0 < 10; ++d0) a += cat[d0]*sWl[co*10+d0];
    x[co] = a > 0.f ? a : 0.f;
  }
  {
    const float4* xp = (const float4*)(t2ws + (size_t)gp*16);
    float4 u0 = xp[0], u1 = xp[1], u2 = xp[2], u3 = xp[3];
    float xv[16] = {u0.x,u0.y,u0.z,u0.w, u1.x,u1.y,u1.z,u1.w,
                    u2.x,u2.y,u2.z,u2.w, u3.x,u3.y,u3.z,u3.w};
#pragma unroll
    for (int c = 0; c < 16; ++c) {
      float v = xv[c]*sa1[c] + sc1[c];
      x[16+c] = v > 0.f ? v : 0.f;
    }
  }
  float tacc0 = sbp[k], tacc1 = sbp[k+16];
#pragma unroll
  for (int co = 0; co < 32; ++co) {
    float s = 0.f;
#pragma unroll
    for (int ci = 0; ci < 32; ++ci) s += x[ci]*sWs[co*32+ci];
    float m = s;
#pragma unroll
    for (int msk = 8; msk > 0; msk >>= 1) m = fmaxf(m, __shfl_xor(m, msk, 16));
    float e = __expf(s - m);
    float se = e;
#pragma unroll
    for (int msk = 8; msk > 0; msk >>= 1) se += __shfl_xor(se, msk, 16);
    float w = e/se;
    float fv = w*x[co];
#pragma unroll
    for (int msk = 8; msk > 0; msk >>= 1) fv += __shfl_xor(fv, msk, 16);
    tacc0 += fv*sWpT[co*32+k];
    tacc1 += fv*sWpT[co*32+k+16];
  }
  t4[(size_t)gp*32 + k]      = tacc0;
  t4[(size_t)gp*32 + k + 16] = tacc1;
  atomicAdd(&lsum[k], tacc0);      atomicAdd(&lsq[k], tacc0*tacc0);
  atomicAdd(&lsum[k+16], tacc1);   atomicAdd(&lsq[k+16], tacc1*tacc1);
  __syncthreads();
  if (tid < 32) { atomicAdd(&stats[S_P2+tid], lsum[tid]); atomicAdd(&stats[S_P2+32+tid], lsq[tid]); }
}

// ---------------- final: mlp2 + BN'd shortcut + leaky 0.01 ----------------
__global__ void k_final(const float* __restrict__ t4ws, const float* __restrict__ features,
                        const float* __restrict__ W2, const float* __restrict__ b2,
                        const float* __restrict__ Wsc, const float* __restrict__ bsc,
                        const float* __restrict__ coef, float* __restrict__ out) {
  __shared__ float sW2[2048], sb2[64], sWscF[512], sbscF[64], sa[32], scc[32];
  int tid = threadIdx.x;
  for (int i = tid; i < 2048; i += 256) sW2[i] = W2[i];
  if (tid < 64) sb2[tid] = b2[tid];
  for (int i = tid; i < 512; i += 256) { int c2 = i >> 3; sWscF[i] = Wsc[i]*coef[C_SC + c2]; }
  if (tid < 64) sbscF[tid] = bsc[tid]*coef[C_SC+tid] + coef[C_SC+64+tid];
  if (tid < 32) { sa[tid] = coef[C_P2+tid]; scc[tid] = coef[C_P2+32+tid]; }
  __syncthreads();
  int q = blockIdx.x*256 + tid;
  int b = q >> 15, n = q & (NPTS-1);
  float x3[32];
  const float4* tp = (const float4*)(t4ws + (size_t)q*32);
#pragma unroll
  for (int i = 0; i < 8; ++i) {
    float4 u = tp[i];
    float v0 = u.x*sa[4*i+0] + scc[4*i+0];
    float v1 = u.y*sa[4*i+1] + scc[4*i+1];
    float v2 = u.z*sa[4*i+2] + scc[4*i+2];
    float v3 = u.w*sa[4*i+3] + scc[4*i+3];
    x3[4*i+0] = v0 > 0.f ? v0 : 0.f;
    x3[4*i+1] = v1 > 0.f ? v1 : 0.f;
    x3[4*i+2] = v2 > 0.f ? v2 : 0.f;
    x3[4*i+3] = v3 > 0.f ? v3 : 0.f;
  }
  float f[8];
#pragma unroll
  for (int c = 0; c < 8; ++c) f[c] = features[((size_t)b*8+c)*NPTS + n];
  for (int c2 = 0; c2 < 64; ++c2) {
    float acc = sb2[c2];
#pragma unroll
    for (int co = 0; co < 32; ++co) acc += x3[co]*sW2[c2*32+co];
    float sv = sbscF[c2];
#pragma unroll
    for (int c = 0; c < 8; ++c) sv += f[c]*sWscF[c2*8+c];
    float o = acc + sv;
    out[((size_t)b*64 + c2)*NPTS + n] = o > 0.f ? o : 0.01f*o;
  }
}

extern "C" void kernel_launch(void* const* d_in, const int* in_sizes, int n_in,
                              void* d_out, int out_size, void* d_ws, size_t ws_size,
                              hipStream_t stream) {
  const float* coords   = (const float*)d_in[0];
  const float* features = (const float*)d_in[1];
  const float* W1  = (const float*)d_in[2];
  const float* b1  = (const float*)d_in[3];
  const float* Wl1 = (const float*)d_in[4];
  const float* bl1 = (const float*)d_in[5];
  const float* gl1 = (const float*)d_in[6];
  const float* bl1b= (const float*)d_in[7];
  const float* Ws1 = (const float*)d_in[8];
  const float* Wp1 = (const float*)d_in[9];
  const float* bp1 = (const float*)d_in[10];
  const float* gp1 = (const float*)d_in[11];
  const float* bp1b= (const float*)d_in[12];
  const float* Wl2 = (const float*)d_in[13];
  const float* bl2 = (const float*)d_in[14];
  const float* gl2 = (const float*)d_in[15];
  const float* bl2b= (const float*)d_in[16];
  const float* Ws2 = (const float*)d_in[17];
  const float* Wp2 = (const float*)d_in[18];
  const float* bp2 = (const float*)d_in[19];
  const float* gp2 = (const float*)d_in[20];
  const float* bp2b= (const float*)d_in[21];
  const float* W2  = (const float*)d_in[22];
  const float* b2  = (const float*)d_in[23];
  const float* Wsc = (const float*)d_in[24];
  const float* bsc = (const float*)d_in[25];
  const float* gsc = (const float*)d_in[26];
  const float* bscb= (const float*)d_in[27];

  float* wsF  = (float*)d_ws;
  int*   wsI  = (int*)d_ws;
  int*   idxp = wsI;
  float* x1p  = wsF + WS_X1;
  float* t2p  = wsF + WS_T2;
  float* t4p  = wsF + WS_T4;
  float* stat = wsF + WS_STAT;
  float* coef = wsF + WS_COEF;
  int*   gcnt = wsI + WS_GCNT;
  int*   gsta = wsI + WS_GSTART;
  int*   gcel = wsI + WS_CELLID;
  int*   sid  = wsI + WS_SORTID;
  float4* csrt = (float4*)(wsF + WS_CSORT);
  unsigned int* bbox = (unsigned int*)(wsI + WS_BBOX);
  int*   hist = wsI + WS_HIST;
  int*   strt = wsI + WS_STARTS;          // aliases hist (dead after k_edges)
  float* edge = wsF + WS_EDGE;
  float* outp = (float*)d_out;

  hipLaunchKernelGGL(k_zero_all, dim3(48), dim3(256), 0, stream, stat, gcnt, hist, bbox);
  hipLaunchKernelGGL(k_bbox,    dim3(NQ/256), dim3(256), 0, stream, coords, bbox);
  hipLaunchKernelGGL(k_hist,    dim3(NQ/256), dim3(256), 0, stream, coords, bbox, hist);
  hipLaunchKernelGGL(k_edges,   dim3(6), dim3(256), 0, stream, hist, bbox, edge);
  hipLaunchKernelGGL(k_bin,     dim3(NQ/256), dim3(256), 0, stream, coords, edge, gcel, gcnt);
  hipLaunchKernelGGL(k_alloc,   dim3(1), dim3(1024), 0, stream, gcnt, gsta, strt);
  hipLaunchKernelGGL(k_scatter, dim3(NQ/256), dim3(256), 0, stream, coords, gcel, gsta, csrt, sid);
  hipLaunchKernelGGL(k_knn_grid,dim3(NQ/16), dim3(256), 0, stream,
                     csrt, sid, strt, edge, idxp);
  hipLaunchKernelGGL(k_mlp1, dim3(NQ/256), dim3(256), 0, stream,
                     features, W1, b1, Wsc, bsc, x1p, stat);
  hipLaunchKernelGGL(k_lsestats, dim3((NQ*KK)/256), dim3(256), 0, stream,
                     coords, idxp, Wl1, bl1, Wl2, bl2, stat);
  hipLaunchKernelGGL(k_bnfin, dim3(1), dim3(64), 0, stream, stat, coef, gl1, bl1b,
                     S_L1, C_L1, 16, 1.f/(float)((size_t)NQ*KK));
  hipLaunchKernelGGL(k_bnfin, dim3(1), dim3(64), 0, stream, stat, coef, gl2, bl2b,
                     S_L2, C_L2, 16, 1.f/(float)((size_t)NQ*KK));
  hipLaunchKernelGGL(k_bnfin, dim3(1), dim3(64), 0, stream, stat, coef, gsc, bscb,
                     S_SC, C_SC, 64, 1.f/(float)NQ);
  hipLaunchKernelGGL(k_att1, dim3(NQ/16), dim3(256), 0, stream,
                     coords, idxp, x1p, Wl1, bl1, Ws1, Wp1, bp1, coef, t2p, stat);
  hipLaunchKernelGGL(k_bnfin, dim3(1), dim3(64), 0, stream, stat, coef, gp1, bp1b,
                     S_P1, C_P1, 16, 1.f/(float)NQ);
  hipLaunchKernelGGL(k_att2, dim3(NQ/16), dim3(256), 0, stream,
                     coords, idxp, t2p, Wl2, bl2, Ws2, Wp2, bp2, coef, t4p, stat);
  hipLaunchKernelGGL(k_bnfin, dim3(1), dim3(64), 0, stream, stat, coef, gp2, bp2b,
                     S_P2, C_P2, 32, 1.f/(float)NQ);
  hipLaunchKernelGGL(k_final, dim3(NQ/256), dim3(256), 0, stream,
                     t4p, features, W2, b2, Wsc, bsc, coef, outp);
}